// Round 1
// baseline (478.821 us; speedup 1.0000x reference)
//
#include <hip/hip_runtime.h>

constexpr int N_NODES = 50000;
constexpr int N_EDGES = 640000;
constexpr int F_H = 128;
constexpr int F_C = 40;

constexpr int SCAN_B = 1024;
constexpr int NB = (N_NODES + SCAN_B - 1) / SCAN_B; // 49

// ---------------- CSR build ----------------

__global__ void init_k(float* deg, int* cnt) {
    int i = blockIdx.x * 256 + threadIdx.x;
    if (i < N_NODES) { deg[i] = 1.0f; cnt[i] = 0; }
}

__global__ void deg_hist_k(const int* __restrict__ dst, const float* __restrict__ ew,
                           float* deg, int* cnt) {
    int e = blockIdx.x * 256 + threadIdx.x;
    if (e < N_EDGES) {
        int d = dst[e];
        atomicAdd(&deg[d], ew[e]);
        atomicAdd(&cnt[d], 1);
    }
}

__global__ void dinv_k(float* deg) {
    int i = blockIdx.x * 256 + threadIdx.x;
    if (i < N_NODES) {
        float d = deg[i];
        deg[i] = (d > 0.f) ? rsqrtf(d) : 0.f;   // deg >= 1 always (self-loop)
    }
}

__global__ void block_sums_k(const int* __restrict__ cnt, int* bsum) {
    __shared__ int s[256];
    int b = blockIdx.x, t = threadIdx.x;
    int base = b * SCAN_B;
    int acc = 0;
    for (int j = t; j < SCAN_B; j += 256) {
        int i = base + j;
        acc += (i < N_NODES) ? cnt[i] : 0;
    }
    s[t] = acc;
    __syncthreads();
    for (int off = 128; off > 0; off >>= 1) {
        if (t < off) s[t] += s[t + off];
        __syncthreads();
    }
    if (t == 0) bsum[b] = s[0];
}

__global__ void scan_sums_k(const int* __restrict__ bsum, int* boff, int* rowptr) {
    if (threadIdx.x == 0 && blockIdx.x == 0) {
        int run = 0;
        for (int i = 0; i < NB; i++) { boff[i] = run; run += bsum[i]; }
        rowptr[N_NODES] = run;   // == N_EDGES
    }
}

__global__ __launch_bounds__(SCAN_B) void scan_within_k(const int* __restrict__ cnt,
        const int* __restrict__ boff, int* rowptr) {
    __shared__ int s[SCAN_B];
    int b = blockIdx.x, t = threadIdx.x;
    int i = b * SCAN_B + t;
    int c = (i < N_NODES) ? cnt[i] : 0;
    int x = c;
    s[t] = x;
    __syncthreads();
    for (int off = 1; off < SCAN_B; off <<= 1) {
        int v = (t >= off) ? s[t - off] : 0;
        __syncthreads();
        x += v;
        s[t] = x;
        __syncthreads();
    }
    if (i < N_NODES) rowptr[i] = boff[b] + x - c;   // exclusive scan
}

__global__ void prep_cursor_k(const int* __restrict__ rowptr, int* cursor) {
    int i = blockIdx.x * 256 + threadIdx.x;
    if (i < N_NODES) cursor[i] = rowptr[i];
}

__global__ void fill_k(const int* __restrict__ src, const int* __restrict__ dst,
                       const float* __restrict__ ew, const float* __restrict__ dinv,
                       int* cursor, int* col, float* val) {
    int e = blockIdx.x * 256 + threadIdx.x;
    if (e < N_EDGES) {
        int d = dst[e], s = src[e];
        int pos = atomicAdd(&cursor[d], 1);
        col[pos] = s;
        val[pos] = dinv[s] * ew[e] * dinv[d];
    }
}

// ---------------- GEMM: H[N,F_OUT] = X[N,128] @ W[128,F_OUT] ----------------
// W staged in LDS (padded to F_PAD cols), 32-row x tile in LDS,
// each thread computes RPT rows x 4 cols in registers.

template<int F_OUT, int F_PAD>
__global__ __launch_bounds__(256) void gemm_k(const float* __restrict__ X,
        const float* __restrict__ W, float* __restrict__ H) {
    constexpr int RB  = 32;            // rows per block
    constexpr int CG  = F_PAD / 4;     // column groups of 4
    constexpr int RG  = 256 / CG;      // row groups
    constexpr int RPT = RB / RG;       // rows per thread
    __shared__ float xs[RB * 128];
    __shared__ float ws[128 * F_PAD];
    int tid = threadIdx.x;
    int row0 = blockIdx.x * RB;

    for (int idx = tid; idx < 128 * F_PAD; idx += 256) {
        int k = idx / F_PAD, c = idx - k * F_PAD;
        ws[idx] = (c < F_OUT) ? W[k * F_OUT + c] : 0.f;
    }
    int rows_in = N_NODES - row0; if (rows_in > RB) rows_in = RB;
    int limit4 = rows_in * 32;                       // float4s of valid x
    const float4* xg = (const float4*)(X + (size_t)row0 * 128);
    float4* xs4 = (float4*)xs;
    for (int idx = tid; idx < RB * 32; idx += 256) {
        float4 v = {0.f, 0.f, 0.f, 0.f};
        if (idx < limit4) v = xg[idx];
        xs4[idx] = v;
    }
    __syncthreads();

    int cg = tid % CG, rg = tid / CG;
    float acc[RPT][4];
    #pragma unroll
    for (int r = 0; r < RPT; r++) { acc[r][0] = acc[r][1] = acc[r][2] = acc[r][3] = 0.f; }

    #pragma unroll 4
    for (int k = 0; k < 128; k++) {
        float4 wv = *(const float4*)&ws[k * F_PAD + cg * 4];
        #pragma unroll
        for (int r = 0; r < RPT; r++) {
            float a = xs[(rg * RPT + r) * 128 + k];
            acc[r][0] = fmaf(a, wv.x, acc[r][0]);
            acc[r][1] = fmaf(a, wv.y, acc[r][1]);
            acc[r][2] = fmaf(a, wv.z, acc[r][2]);
            acc[r][3] = fmaf(a, wv.w, acc[r][3]);
        }
    }

    #pragma unroll
    for (int r = 0; r < RPT; r++) {
        int row = row0 + rg * RPT + r;
        if (row < N_NODES) {
            int cb = cg * 4;
            if constexpr (F_OUT == F_PAD) {
                float4 v = {acc[r][0], acc[r][1], acc[r][2], acc[r][3]};
                *(float4*)&H[(size_t)row * F_OUT + cb] = v;
            } else {
                #pragma unroll
                for (int j = 0; j < 4; j++)
                    if (cb + j < F_OUT) H[(size_t)row * F_OUT + cb + j] = acc[r][j];
            }
        }
    }
}

// ---------------- Aggregation: out[i] = sum_{e: dst==i} val[e]*H[col[e]] + dinv[i]^2*H[i] + b ----------------

template<bool RELU>
__global__ __launch_bounds__(64) void agg128_k(const float* __restrict__ Hh,
        const int* __restrict__ col, const float* __restrict__ val,
        const int* __restrict__ rowptr, const float* __restrict__ dinv,
        const float* __restrict__ bias, float* __restrict__ out) {
    int i = blockIdx.x;
    int f = threadIdx.x;            // handles cols 2f, 2f+1
    float di = dinv[i];
    float sn = di * di;
    float2 hs = *(const float2*)&Hh[(size_t)i * 128 + 2 * f];
    float ax = sn * hs.x, ay = sn * hs.y;
    int e0 = rowptr[i], e1 = rowptr[i + 1];
    for (int e = e0; e < e1; e++) {
        int c = col[e];
        float v = val[e];
        float2 hv = *(const float2*)&Hh[(size_t)c * 128 + 2 * f];
        ax = fmaf(v, hv.x, ax);
        ay = fmaf(v, hv.y, ay);
    }
    float2 b = *(const float2*)&bias[2 * f];
    ax += b.x; ay += b.y;
    if (RELU) { ax = fmaxf(ax, 0.f); ay = fmaxf(ay, 0.f); }
    float2 o; o.x = ax; o.y = ay;
    *(float2*)&out[(size_t)i * 128 + 2 * f] = o;
}

__global__ __launch_bounds__(128) void agg40_k(const float* __restrict__ Hh,
        const int* __restrict__ col, const float* __restrict__ val,
        const int* __restrict__ rowptr, const float* __restrict__ dinv,
        const float* __restrict__ bias, float* __restrict__ out) {
    int node = blockIdx.x * 2 + (threadIdx.x >> 6);
    int f = threadIdx.x & 63;
    if (f >= F_C) return;
    float di = dinv[node];
    float acc = di * di * Hh[(size_t)node * F_C + f];
    int e0 = rowptr[node], e1 = rowptr[node + 1];
    for (int e = e0; e < e1; e++) {
        acc = fmaf(val[e], Hh[(size_t)col[e] * F_C + f], acc);
    }
    out[(size_t)node * F_C + f] = acc + bias[f];
}

// ---------------- launch ----------------

extern "C" void kernel_launch(void* const* d_in, const int* in_sizes, int n_in,
                              void* d_out, int out_size, void* d_ws, size_t ws_size,
                              hipStream_t stream) {
    const float* x  = (const float*)d_in[0];
    const int*   ei = (const int*)d_in[1];
    const int*   src = ei;
    const int*   dst = ei + N_EDGES;
    const float* ew = (const float*)d_in[2];
    const float* W1 = (const float*)d_in[3];
    const float* b1 = (const float*)d_in[4];
    const float* W2 = (const float*)d_in[5];
    const float* b2 = (const float*)d_in[6];
    const float* W3 = (const float*)d_in[7];
    const float* b3 = (const float*)d_in[8];
    float* out = (float*)d_out;

    char* w = (char*)d_ws;
    auto alloc = [&](size_t bytes) {
        char* p = w;
        w += (bytes + 255) & ~(size_t)255;
        return p;
    };
    float* dinv   = (float*)alloc((size_t)N_NODES * 4);
    int*   rowptr = (int*)  alloc((size_t)(N_NODES + 1) * 4);
    int*   cursor = (int*)  alloc((size_t)N_NODES * 4);   // doubles as counts
    int*   bsum   = (int*)  alloc((size_t)NB * 4);
    int*   boff   = (int*)  alloc((size_t)NB * 4);
    int*   col    = (int*)  alloc((size_t)N_EDGES * 4);
    float* val    = (float*)alloc((size_t)N_EDGES * 4);
    float* hbuf   = (float*)alloc((size_t)N_NODES * 128 * 4);
    float* abuf   = (float*)alloc((size_t)N_NODES * 128 * 4);

    int gN = (N_NODES + 255) / 256;
    int gE = (N_EDGES + 255) / 256;

    init_k<<<gN, 256, 0, stream>>>(dinv, cursor);
    deg_hist_k<<<gE, 256, 0, stream>>>(dst, ew, dinv, cursor);
    dinv_k<<<gN, 256, 0, stream>>>(dinv);
    block_sums_k<<<NB, 256, 0, stream>>>(cursor, bsum);
    scan_sums_k<<<1, 64, 0, stream>>>(bsum, boff, rowptr);
    scan_within_k<<<NB, SCAN_B, 0, stream>>>(cursor, boff, rowptr);
    prep_cursor_k<<<gN, 256, 0, stream>>>(rowptr, cursor);
    fill_k<<<gE, 256, 0, stream>>>(src, dst, ew, dinv, cursor, col, val);

    constexpr int GB = (N_NODES + 31) / 32;
    gemm_k<128, 128><<<GB, 256, 0, stream>>>(x, W1, hbuf);
    agg128_k<true><<<N_NODES, 64, 0, stream>>>(hbuf, col, val, rowptr, dinv, b1, abuf);
    gemm_k<128, 128><<<GB, 256, 0, stream>>>(abuf, W2, hbuf);
    agg128_k<true><<<N_NODES, 64, 0, stream>>>(hbuf, col, val, rowptr, dinv, b2, abuf);
    gemm_k<40, 64><<<GB, 256, 0, stream>>>(abuf, W3, hbuf);
    agg40_k<<<N_NODES / 2, 128, 0, stream>>>(hbuf, col, val, rowptr, dinv, b3, out);
}

// Round 2
// 436.369 us; speedup vs baseline: 1.0973x; 1.0973x over previous
//
#include <hip/hip_runtime.h>

constexpr int N_NODES = 50000;
constexpr int N_EDGES = 640000;
constexpr int F_C = 40;

constexpr int SCAN_B = 1024;
constexpr int NB = (N_NODES + SCAN_B - 1) / SCAN_B; // 49

// ---------------- CSR build ----------------

__global__ void init_k(float* deg, int* cnt) {
    int i = blockIdx.x * 256 + threadIdx.x;
    if (i < N_NODES) { deg[i] = 1.0f; cnt[i] = 0; }
}

__global__ void deg_hist_k(const int* __restrict__ dst, const float* __restrict__ ew,
                           float* deg, int* cnt) {
    int e = blockIdx.x * 256 + threadIdx.x;
    if (e < N_EDGES) {
        int d = dst[e];
        atomicAdd(&deg[d], ew[e]);
        atomicAdd(&cnt[d], 1);
    }
}

__global__ void dinv_k(float* deg) {
    int i = blockIdx.x * 256 + threadIdx.x;
    if (i < N_NODES) {
        float d = deg[i];
        deg[i] = (d > 0.f) ? rsqrtf(d) : 0.f;   // deg >= 1 always (self-loop)
    }
}

__global__ void block_sums_k(const int* __restrict__ cnt, int* bsum) {
    __shared__ int s[256];
    int b = blockIdx.x, t = threadIdx.x;
    int base = b * SCAN_B;
    int acc = 0;
    for (int j = t; j < SCAN_B; j += 256) {
        int i = base + j;
        acc += (i < N_NODES) ? cnt[i] : 0;
    }
    s[t] = acc;
    __syncthreads();
    for (int off = 128; off > 0; off >>= 1) {
        if (t < off) s[t] += s[t + off];
        __syncthreads();
    }
    if (t == 0) bsum[b] = s[0];
}

__global__ void scan_sums_k(const int* __restrict__ bsum, int* boff, int* rowptr) {
    if (threadIdx.x == 0 && blockIdx.x == 0) {
        int run = 0;
        for (int i = 0; i < NB; i++) { boff[i] = run; run += bsum[i]; }
        rowptr[N_NODES] = run;   // == N_EDGES
    }
}

// exclusive scan within block; also writes the fill-cursor copy
__global__ __launch_bounds__(SCAN_B) void scan_within_k(const int* __restrict__ cnt,
        const int* __restrict__ boff, int* rowptr, int* cursor) {
    __shared__ int s[SCAN_B];
    int b = blockIdx.x, t = threadIdx.x;
    int i = b * SCAN_B + t;
    int c = (i < N_NODES) ? cnt[i] : 0;
    int x = c;
    s[t] = x;
    __syncthreads();
    for (int off = 1; off < SCAN_B; off <<= 1) {
        int v = (t >= off) ? s[t - off] : 0;
        __syncthreads();
        x += v;
        s[t] = x;
        __syncthreads();
    }
    if (i < N_NODES) {
        int rp = boff[b] + x - c;    // exclusive scan
        rowptr[i] = rp;
        cursor[i] = rp;
    }
}

// packs (col, val-bits) into int2 per edge, dst-sorted
__global__ void fill_k(const int* __restrict__ src, const int* __restrict__ dst,
                       const float* __restrict__ ew, const float* __restrict__ dinv,
                       int* cursor, int2* ev) {
    int e = blockIdx.x * 256 + threadIdx.x;
    if (e < N_EDGES) {
        int d = dst[e], s = src[e];
        int pos = atomicAdd(&cursor[d], 1);
        float v = dinv[s] * ew[e] * dinv[d];
        ev[pos] = make_int2(s, __float_as_int(v));
    }
}

// ---------------- GEMM: H[N,F_OUT] = X[N,128] @ W[128,F_OUT] (+bias) ----------------

template<int F_OUT, int F_PAD, bool BIAS>
__global__ __launch_bounds__(256) void gemm_k(const float* __restrict__ X,
        const float* __restrict__ W, const float* __restrict__ bias,
        float* __restrict__ H) {
    constexpr int RB  = 32;            // rows per block
    constexpr int CG  = F_PAD / 4;     // column groups of 4
    constexpr int RG  = 256 / CG;      // row groups
    constexpr int RPT = RB / RG;       // rows per thread
    __shared__ float xs[RB * 128];
    __shared__ float ws[128 * F_PAD];
    int tid = threadIdx.x;
    int row0 = blockIdx.x * RB;

    for (int idx = tid; idx < 128 * F_PAD; idx += 256) {
        int k = idx / F_PAD, c = idx - k * F_PAD;
        ws[idx] = (c < F_OUT) ? W[k * F_OUT + c] : 0.f;
    }
    int rows_in = N_NODES - row0; if (rows_in > RB) rows_in = RB;
    int limit4 = rows_in * 32;                       // float4s of valid x
    const float4* xg = (const float4*)(X + (size_t)row0 * 128);
    float4* xs4 = (float4*)xs;
    for (int idx = tid; idx < RB * 32; idx += 256) {
        float4 v = {0.f, 0.f, 0.f, 0.f};
        if (idx < limit4) v = xg[idx];
        xs4[idx] = v;
    }
    __syncthreads();

    int cg = tid % CG, rg = tid / CG;
    float acc[RPT][4];
    #pragma unroll
    for (int r = 0; r < RPT; r++) { acc[r][0] = acc[r][1] = acc[r][2] = acc[r][3] = 0.f; }

    #pragma unroll 4
    for (int k = 0; k < 128; k++) {
        float4 wv = *(const float4*)&ws[k * F_PAD + cg * 4];
        #pragma unroll
        for (int r = 0; r < RPT; r++) {
            float a = xs[(rg * RPT + r) * 128 + k];
            acc[r][0] = fmaf(a, wv.x, acc[r][0]);
            acc[r][1] = fmaf(a, wv.y, acc[r][1]);
            acc[r][2] = fmaf(a, wv.z, acc[r][2]);
            acc[r][3] = fmaf(a, wv.w, acc[r][3]);
        }
    }

    #pragma unroll
    for (int r = 0; r < RPT; r++) {
        int row = row0 + rg * RPT + r;
        if (row < N_NODES) {
            int cb = cg * 4;
            if constexpr (F_OUT == F_PAD) {
                float4 v = {acc[r][0], acc[r][1], acc[r][2], acc[r][3]};
                if constexpr (BIAS) {
                    v.x += bias[cb]; v.y += bias[cb + 1];
                    v.z += bias[cb + 2]; v.w += bias[cb + 3];
                }
                *(float4*)&H[(size_t)row * F_OUT + cb] = v;
            } else {
                #pragma unroll
                for (int j = 0; j < 4; j++)
                    if (cb + j < F_OUT) {
                        float o = acc[r][j];
                        if constexpr (BIAS) o += bias[cb + j];
                        H[(size_t)row * F_OUT + cb + j] = o;
                    }
            }
        }
    }
}

// ---------------- Aggregation: out[i] = sum_e val[e]*H[col[e]] + dinv[i]^2*H[i] (+bias,relu) ----------------
// 256 threads = 4 waves, one node per wave; lane handles feature pair (2f, 2f+1).
// Edge metadata is wave-uniform (scalar loads); edge loop unrolled x4 for MLP.

template<int MODE>   // 0: plain, 1: +bias +relu
__global__ __launch_bounds__(256) void agg128_k(const float* __restrict__ H,
        const int2* __restrict__ ev, const int* __restrict__ rowptr,
        const float* __restrict__ dinv, const float* __restrict__ bias,
        float* __restrict__ out) {
    int lane = threadIdx.x & 63;
    int node = __builtin_amdgcn_readfirstlane(blockIdx.x * 4 + (threadIdx.x >> 6));
    if (node >= N_NODES) return;
    const float2* __restrict__ H2 = (const float2*)H;
    float di = dinv[node];
    float sn = di * di;
    float2 hs = H2[(size_t)node * 64 + lane];
    float ax = sn * hs.x, ay = sn * hs.y;
    int e0 = rowptr[node], e1 = rowptr[node + 1];
    int e = e0;
    for (; e + 4 <= e1; e += 4) {
        int2 p0 = ev[e + 0];
        int2 p1 = ev[e + 1];
        int2 p2 = ev[e + 2];
        int2 p3 = ev[e + 3];
        float2 g0 = H2[(size_t)p0.x * 64 + lane];
        float2 g1 = H2[(size_t)p1.x * 64 + lane];
        float2 g2 = H2[(size_t)p2.x * 64 + lane];
        float2 g3 = H2[(size_t)p3.x * 64 + lane];
        float v0 = __int_as_float(p0.y), v1 = __int_as_float(p1.y);
        float v2 = __int_as_float(p2.y), v3 = __int_as_float(p3.y);
        ax = fmaf(v0, g0.x, ax); ay = fmaf(v0, g0.y, ay);
        ax = fmaf(v1, g1.x, ax); ay = fmaf(v1, g1.y, ay);
        ax = fmaf(v2, g2.x, ax); ay = fmaf(v2, g2.y, ay);
        ax = fmaf(v3, g3.x, ax); ay = fmaf(v3, g3.y, ay);
    }
    for (; e < e1; e++) {
        int2 p = ev[e];
        float2 g = H2[(size_t)p.x * 64 + lane];
        float v = __int_as_float(p.y);
        ax = fmaf(v, g.x, ax);
        ay = fmaf(v, g.y, ay);
    }
    if constexpr (MODE == 1) {
        float2 b = *(const float2*)&bias[2 * lane];
        ax = fmaxf(ax + b.x, 0.f);
        ay = fmaxf(ay + b.y, 0.f);
    }
    float2 o; o.x = ax; o.y = ay;
    *(float2*)&out[(size_t)node * 128 + 2 * lane] = o;
}

// ---------------- launch ----------------

extern "C" void kernel_launch(void* const* d_in, const int* in_sizes, int n_in,
                              void* d_out, int out_size, void* d_ws, size_t ws_size,
                              hipStream_t stream) {
    const float* x  = (const float*)d_in[0];
    const int*   ei = (const int*)d_in[1];
    const int*   src = ei;
    const int*   dst = ei + N_EDGES;
    const float* ew = (const float*)d_in[2];
    const float* W1 = (const float*)d_in[3];
    const float* b1 = (const float*)d_in[4];
    const float* W2 = (const float*)d_in[5];
    const float* b2 = (const float*)d_in[6];
    const float* W3 = (const float*)d_in[7];
    const float* b3 = (const float*)d_in[8];
    float* out = (float*)d_out;

    char* w = (char*)d_ws;
    auto alloc = [&](size_t bytes) {
        char* p = w;
        w += (bytes + 255) & ~(size_t)255;
        return p;
    };
    float* dinv   = (float*)alloc((size_t)N_NODES * 4);
    int*   rowptr = (int*)  alloc((size_t)(N_NODES + 1) * 4);
    int*   cursor = (int*)  alloc((size_t)N_NODES * 4);   // doubles as counts
    int*   bsum   = (int*)  alloc((size_t)NB * 4);
    int*   boff   = (int*)  alloc((size_t)NB * 4);
    int2*  ev     = (int2*) alloc((size_t)N_EDGES * 8);
    float* hbuf   = (float*)alloc((size_t)N_NODES * 128 * 4);
    float* abuf   = (float*)alloc((size_t)N_NODES * 128 * 4);

    int gN = (N_NODES + 255) / 256;
    int gE = (N_EDGES + 255) / 256;

    init_k<<<gN, 256, 0, stream>>>(dinv, cursor);
    deg_hist_k<<<gE, 256, 0, stream>>>(dst, ew, dinv, cursor);
    dinv_k<<<gN, 256, 0, stream>>>(dinv);
    block_sums_k<<<NB, 256, 0, stream>>>(cursor, bsum);
    scan_sums_k<<<1, 64, 0, stream>>>(bsum, boff, rowptr);
    scan_within_k<<<NB, SCAN_B, 0, stream>>>(cursor, boff, rowptr, cursor);
    fill_k<<<gE, 256, 0, stream>>>(src, dst, ew, dinv, cursor, ev);

    constexpr int GB = (N_NODES + 31) / 32;
    constexpr int GA = (N_NODES + 3) / 4;
    gemm_k<128, 128, false><<<GB, 256, 0, stream>>>(x, W1, nullptr, hbuf);
    agg128_k<1><<<GA, 256, 0, stream>>>(hbuf, ev, rowptr, dinv, b1, abuf);
    gemm_k<128, 128, false><<<GB, 256, 0, stream>>>(abuf, W2, nullptr, hbuf);
    agg128_k<1><<<GA, 256, 0, stream>>>(hbuf, ev, rowptr, dinv, b2, abuf);
    agg128_k<0><<<GA, 256, 0, stream>>>(abuf, ev, rowptr, dinv, nullptr, hbuf);
    gemm_k<40, 64, true><<<GB, 256, 0, stream>>>(hbuf, W3, b3, out);
}

// Round 3
// 422.687 us; speedup vs baseline: 1.1328x; 1.0324x over previous
//
#include <hip/hip_runtime.h>

constexpr int N_NODES = 50000;
constexpr int N_EDGES = 640000;

constexpr int SCAN_B = 1024;
constexpr int NB = (N_NODES + SCAN_B - 1) / SCAN_B; // 49

constexpr int GB128 = (N_NODES + 31) / 32;          // gemm blocks (RB=32)
constexpr int HB    = (N_EDGES + 255) / 256;        // hist blocks

// ---------------- small utility ----------------

__global__ void zero_k(int* cnt) {
    int i = blockIdx.x * 256 + threadIdx.x;
    if (i < N_NODES) cnt[i] = 0;
}

// ---------------- GEMM (optionally fused with edge histogram) ----------------
// If FUSE_HIST: blocks [0, HB) do the dst histogram, blocks [HB, HB+GB) do the GEMM.

template<int F_OUT, int F_PAD, bool BIAS, bool FUSE_HIST>
__global__ __launch_bounds__(256) void gemm_hist_k(const float* __restrict__ X,
        const float* __restrict__ W, const float* __restrict__ bias,
        float* __restrict__ H, const int* __restrict__ dst, int* cnt) {
    if constexpr (FUSE_HIST) {
        if (blockIdx.x < HB) {
            int e = blockIdx.x * 256 + threadIdx.x;
            if (e < N_EDGES) atomicAdd(&cnt[dst[e]], 1);
            return;
        }
    }
    int bid = FUSE_HIST ? (blockIdx.x - HB) : blockIdx.x;

    constexpr int RB  = 32;            // rows per block
    constexpr int CG  = F_PAD / 4;     // column groups of 4
    constexpr int RG  = 256 / CG;      // row groups
    constexpr int RPT = RB / RG;       // rows per thread
    __shared__ float xs[RB * 128];
    __shared__ float ws[128 * F_PAD];
    int tid = threadIdx.x;
    int row0 = bid * RB;

    for (int idx = tid; idx < 128 * F_PAD; idx += 256) {
        int k = idx / F_PAD, c = idx - k * F_PAD;
        ws[idx] = (c < F_OUT) ? W[k * F_OUT + c] : 0.f;
    }
    int rows_in = N_NODES - row0; if (rows_in > RB) rows_in = RB;
    int limit4 = rows_in * 32;
    const float4* xg = (const float4*)(X + (size_t)row0 * 128);
    float4* xs4 = (float4*)xs;
    for (int idx = tid; idx < RB * 32; idx += 256) {
        float4 v = {0.f, 0.f, 0.f, 0.f};
        if (idx < limit4) v = xg[idx];
        xs4[idx] = v;
    }
    __syncthreads();

    int cg = tid % CG, rg = tid / CG;
    float acc[RPT][4];
    #pragma unroll
    for (int r = 0; r < RPT; r++) { acc[r][0] = acc[r][1] = acc[r][2] = acc[r][3] = 0.f; }

    #pragma unroll 4
    for (int k = 0; k < 128; k++) {
        float4 wv = *(const float4*)&ws[k * F_PAD + cg * 4];
        #pragma unroll
        for (int r = 0; r < RPT; r++) {
            float a = xs[(rg * RPT + r) * 128 + k];
            acc[r][0] = fmaf(a, wv.x, acc[r][0]);
            acc[r][1] = fmaf(a, wv.y, acc[r][1]);
            acc[r][2] = fmaf(a, wv.z, acc[r][2]);
            acc[r][3] = fmaf(a, wv.w, acc[r][3]);
        }
    }

    #pragma unroll
    for (int r = 0; r < RPT; r++) {
        int row = row0 + rg * RPT + r;
        if (row < N_NODES) {
            int cb = cg * 4;
            if constexpr (F_OUT == F_PAD) {
                float4 v = {acc[r][0], acc[r][1], acc[r][2], acc[r][3]};
                if constexpr (BIAS) {
                    v.x += bias[cb]; v.y += bias[cb + 1];
                    v.z += bias[cb + 2]; v.w += bias[cb + 3];
                }
                *(float4*)&H[(size_t)row * F_OUT + cb] = v;
            } else {
                #pragma unroll
                for (int j = 0; j < 4; j++)
                    if (cb + j < F_OUT) {
                        float o = acc[r][j];
                        if constexpr (BIAS) o += bias[cb + j];
                        H[(size_t)row * F_OUT + cb + j] = o;
                    }
            }
        }
    }
}

// ---------------- scan ----------------

__global__ void block_sums_k(const int* __restrict__ cnt, int* bsum) {
    __shared__ int s[256];
    int b = blockIdx.x, t = threadIdx.x;
    int base = b * SCAN_B;
    int acc = 0;
    for (int j = t; j < SCAN_B; j += 256) {
        int i = base + j;
        acc += (i < N_NODES) ? cnt[i] : 0;
    }
    s[t] = acc;
    __syncthreads();
    for (int off = 128; off > 0; off >>= 1) {
        if (t < off) s[t] += s[t + off];
        __syncthreads();
    }
    if (t == 0) bsum[b] = s[0];
}

// exclusive scan within block; block offset computed inline by wave 0 (NB<=64);
// writes rowptr and the fill-cursor copy; last block writes rowptr[N].
__global__ __launch_bounds__(SCAN_B) void scan_within_k(const int* __restrict__ cnt,
        const int* __restrict__ bsum, int* rowptr, int* cursor) {
    __shared__ int s[SCAN_B];
    __shared__ int base_s;
    int b = blockIdx.x, t = threadIdx.x;
    if (t < 64) {
        int v = (t < b) ? bsum[t] : 0;          // NB = 49 <= 64
        #pragma unroll
        for (int off = 32; off > 0; off >>= 1) v += __shfl_down(v, off, 64);
        if (t == 0) base_s = v;
    }
    int i = b * SCAN_B + t;
    int c = (i < N_NODES) ? cnt[i] : 0;
    int x = c;
    s[t] = x;
    __syncthreads();
    for (int off = 1; off < SCAN_B; off <<= 1) {
        int v = (t >= off) ? s[t - off] : 0;
        __syncthreads();
        x += v;
        s[t] = x;
        __syncthreads();
    }
    int base = base_s;
    if (i < N_NODES) {
        int rp = base + x - c;
        rowptr[i] = rp;
        cursor[i] = rp;
    }
    if (b == NB - 1 && t == SCAN_B - 1) rowptr[N_NODES] = base + x;
}

// ---------------- fill (dst-bucketed edge list; stores raw ew bits) ----------------

__global__ void fill_k(const int* __restrict__ src, const int* __restrict__ dst,
                       const float* __restrict__ ew, int* cursor, int2* ev) {
    int e = blockIdx.x * 256 + threadIdx.x;
    if (e < N_EDGES) {
        int pos = atomicAdd(&cursor[dst[e]], 1);
        ev[pos] = make_int2(src[e], __float_as_int(ew[e]));
    }
}

// ---------------- degree + edge scaling from the built CSR ----------------

__global__ void deg_k(const int2* __restrict__ ev, const int* __restrict__ rowptr,
                      float* dinv) {
    int i = blockIdx.x * 256 + threadIdx.x;
    if (i >= N_NODES) return;
    int e0 = rowptr[i], e1 = rowptr[i + 1];
    float s = 1.0f;                              // self-loop weight
    for (int e = e0; e < e1; e++) s += __int_as_float(ev[e].y);
    dinv[i] = rsqrtf(s);
}

__global__ void scale_k(int2* ev, const int* __restrict__ rowptr,
                        const float* __restrict__ dinv) {
    int i = blockIdx.x * 256 + threadIdx.x;
    if (i >= N_NODES) return;
    int e0 = rowptr[i], e1 = rowptr[i + 1];
    float di = dinv[i];
    for (int e = e0; e < e1; e++) {
        int2 p = ev[e];
        ev[e].y = __float_as_int(__int_as_float(p.y) * dinv[p.x] * di);
    }
}

// ---------------- Aggregation ----------------
// 4 waves/block, one node per wave; lane handles feature pair (2f, 2f+1).

template<int MODE>   // 0: plain, 1: +bias +relu
__global__ __launch_bounds__(256) void agg128_k(const float* __restrict__ H,
        const int2* __restrict__ ev, const int* __restrict__ rowptr,
        const float* __restrict__ dinv, const float* __restrict__ bias,
        float* __restrict__ out) {
    int lane = threadIdx.x & 63;
    int node = __builtin_amdgcn_readfirstlane(blockIdx.x * 4 + (threadIdx.x >> 6));
    if (node >= N_NODES) return;
    const float2* __restrict__ H2 = (const float2*)H;
    float di = dinv[node];
    float sn = di * di;
    float2 hs = H2[(size_t)node * 64 + lane];
    float ax = sn * hs.x, ay = sn * hs.y;
    int e0 = rowptr[node], e1 = rowptr[node + 1];
    int e = e0;
    for (; e + 4 <= e1; e += 4) {
        int2 p0 = ev[e + 0];
        int2 p1 = ev[e + 1];
        int2 p2 = ev[e + 2];
        int2 p3 = ev[e + 3];
        float2 g0 = H2[(size_t)p0.x * 64 + lane];
        float2 g1 = H2[(size_t)p1.x * 64 + lane];
        float2 g2 = H2[(size_t)p2.x * 64 + lane];
        float2 g3 = H2[(size_t)p3.x * 64 + lane];
        float v0 = __int_as_float(p0.y), v1 = __int_as_float(p1.y);
        float v2 = __int_as_float(p2.y), v3 = __int_as_float(p3.y);
        ax = fmaf(v0, g0.x, ax); ay = fmaf(v0, g0.y, ay);
        ax = fmaf(v1, g1.x, ax); ay = fmaf(v1, g1.y, ay);
        ax = fmaf(v2, g2.x, ax); ay = fmaf(v2, g2.y, ay);
        ax = fmaf(v3, g3.x, ax); ay = fmaf(v3, g3.y, ay);
    }
    for (; e < e1; e++) {
        int2 p = ev[e];
        float2 g = H2[(size_t)p.x * 64 + lane];
        float v = __int_as_float(p.y);
        ax = fmaf(v, g.x, ax);
        ay = fmaf(v, g.y, ay);
    }
    if constexpr (MODE == 1) {
        float2 b = *(const float2*)&bias[2 * lane];
        ax = fmaxf(ax + b.x, 0.f);
        ay = fmaxf(ay + b.y, 0.f);
    }
    float2 o; o.x = ax; o.y = ay;
    *(float2*)&out[(size_t)node * 128 + 2 * lane] = o;
}

// ---------------- launch ----------------

extern "C" void kernel_launch(void* const* d_in, const int* in_sizes, int n_in,
                              void* d_out, int out_size, void* d_ws, size_t ws_size,
                              hipStream_t stream) {
    const float* x  = (const float*)d_in[0];
    const int*   ei = (const int*)d_in[1];
    const int*   src = ei;
    const int*   dst = ei + N_EDGES;
    const float* ew = (const float*)d_in[2];
    const float* W1 = (const float*)d_in[3];
    const float* b1 = (const float*)d_in[4];
    const float* W2 = (const float*)d_in[5];
    const float* b2 = (const float*)d_in[6];
    const float* W3 = (const float*)d_in[7];
    const float* b3 = (const float*)d_in[8];
    float* out = (float*)d_out;

    char* w = (char*)d_ws;
    auto alloc = [&](size_t bytes) {
        char* p = w;
        w += (bytes + 255) & ~(size_t)255;
        return p;
    };
    float* dinv   = (float*)alloc((size_t)N_NODES * 4);
    int*   rowptr = (int*)  alloc((size_t)(N_NODES + 1) * 4);
    int*   cursor = (int*)  alloc((size_t)N_NODES * 4);   // counts, then fill cursor
    int*   bsum   = (int*)  alloc((size_t)NB * 4);
    int2*  ev     = (int2*) alloc((size_t)N_EDGES * 8);
    float* hbuf   = (float*)alloc((size_t)N_NODES * 128 * 4);
    float* abuf   = (float*)alloc((size_t)N_NODES * 128 * 4);

    int gN = (N_NODES + 255) / 256;
    constexpr int GA = (N_NODES + 3) / 4;

    zero_k<<<gN, 256, 0, stream>>>(cursor);
    // fused: dst histogram + gemm1 (x @ W1 -> hbuf)
    gemm_hist_k<128, 128, false, true><<<HB + GB128, 256, 0, stream>>>(
        x, W1, nullptr, hbuf, dst, cursor);
    block_sums_k<<<NB, 256, 0, stream>>>(cursor, bsum);
    scan_within_k<<<NB, SCAN_B, 0, stream>>>(cursor, bsum, rowptr, cursor);
    fill_k<<<HB, 256, 0, stream>>>(src, dst, ew, cursor, ev);
    deg_k<<<gN, 256, 0, stream>>>(ev, rowptr, dinv);
    scale_k<<<gN, 256, 0, stream>>>(ev, rowptr, dinv);

    agg128_k<1><<<GA, 256, 0, stream>>>(hbuf, ev, rowptr, dinv, b1, abuf);
    gemm_hist_k<128, 128, false, false><<<GB128, 256, 0, stream>>>(
        abuf, W2, nullptr, hbuf, nullptr, nullptr);
    agg128_k<1><<<GA, 256, 0, stream>>>(hbuf, ev, rowptr, dinv, b2, abuf);
    agg128_k<0><<<GA, 256, 0, stream>>>(abuf, ev, rowptr, dinv, nullptr, hbuf);
    gemm_hist_k<40, 64, true, false><<<GB128, 256, 0, stream>>>(
        hbuf, W3, b3, out, nullptr, nullptr);
}

// Round 4
// 386.228 us; speedup vs baseline: 1.2397x; 1.0944x over previous
//
#include <hip/hip_runtime.h>

constexpr int N_NODES = 50000;
constexpr int N_EDGES = 640000;

constexpr int SCAN_B = 1024;
constexpr int NB = (N_NODES + SCAN_B - 1) / SCAN_B; // 49

constexpr int GB128 = (N_NODES + 31) / 32;          // gemm blocks (RB=32)
constexpr int HB    = (N_EDGES + 255) / 256;        // edge-pass blocks

// ---------------- small utility ----------------

__global__ void zero_k(int* cnt) {
    int i = blockIdx.x * 256 + threadIdx.x;
    if (i < N_NODES) cnt[i] = 0;
}

// ---------------- GEMM 128x128 (optionally fused with rank pass) ----------------
// Blocks [0,HB): rank[e] = atomicAdd(cnt[dst[e]],1).  Blocks [HB,..): GEMM.
// W is NOT staged in LDS: streamed via L1/L2 as float4 (64 KB, shared by all blocks).
// LDS = 16 KB X-tile -> high occupancy.

template<bool FUSE_RANK>
__global__ __launch_bounds__(256) void gemm128_k(const float* __restrict__ X,
        const float* __restrict__ W, float* __restrict__ H,
        const int* __restrict__ dst, int* cnt, int* rank) {
    if constexpr (FUSE_RANK) {
        if (blockIdx.x < HB) {
            int e = blockIdx.x * 256 + threadIdx.x;
            if (e < N_EDGES) rank[e] = atomicAdd(&cnt[dst[e]], 1);
            return;
        }
    }
    int bid = FUSE_RANK ? (int)blockIdx.x - HB : (int)blockIdx.x;

    constexpr int RB = 32;
    __shared__ float4 xs4[RB * 32];      // 32 rows x 128 floats
    int tid = threadIdx.x;
    int row0 = bid * RB;

    int rows_in = N_NODES - row0; if (rows_in > RB) rows_in = RB;
    int limit4 = rows_in * 32;
    const float4* xg = (const float4*)(X + (size_t)row0 * 128);
    for (int idx = tid; idx < RB * 32; idx += 256) {
        float4 v = {0.f, 0.f, 0.f, 0.f};
        if (idx < limit4) v = xg[idx];
        xs4[idx] = v;
    }
    __syncthreads();

    int cg = tid & 31;        // column group: 4 cols
    int rg = tid >> 5;        // row group: 4 rows
    const float4* Wg = (const float4*)W;   // W[k][c], 32 float4 per row

    float4 acc[4];
    #pragma unroll
    for (int r = 0; r < 4; r++) acc[r] = make_float4(0.f, 0.f, 0.f, 0.f);

    #pragma unroll 2
    for (int kc = 0; kc < 32; kc++) {
        float4 w0 = Wg[(4 * kc + 0) * 32 + cg];
        float4 w1 = Wg[(4 * kc + 1) * 32 + cg];
        float4 w2 = Wg[(4 * kc + 2) * 32 + cg];
        float4 w3 = Wg[(4 * kc + 3) * 32 + cg];
        #pragma unroll
        for (int r = 0; r < 4; r++) {
            float4 a = xs4[(rg * 4 + r) * 32 + kc];
            acc[r].x = fmaf(a.x, w0.x, acc[r].x);
            acc[r].y = fmaf(a.x, w0.y, acc[r].y);
            acc[r].z = fmaf(a.x, w0.z, acc[r].z);
            acc[r].w = fmaf(a.x, w0.w, acc[r].w);
            acc[r].x = fmaf(a.y, w1.x, acc[r].x);
            acc[r].y = fmaf(a.y, w1.y, acc[r].y);
            acc[r].z = fmaf(a.y, w1.z, acc[r].z);
            acc[r].w = fmaf(a.y, w1.w, acc[r].w);
            acc[r].x = fmaf(a.z, w2.x, acc[r].x);
            acc[r].y = fmaf(a.z, w2.y, acc[r].y);
            acc[r].z = fmaf(a.z, w2.z, acc[r].z);
            acc[r].w = fmaf(a.z, w2.w, acc[r].w);
            acc[r].x = fmaf(a.w, w3.x, acc[r].x);
            acc[r].y = fmaf(a.w, w3.y, acc[r].y);
            acc[r].z = fmaf(a.w, w3.z, acc[r].z);
            acc[r].w = fmaf(a.w, w3.w, acc[r].w);
        }
    }

    #pragma unroll
    for (int r = 0; r < 4; r++) {
        int row = row0 + rg * 4 + r;
        if (row < N_NODES)
            *(float4*)&H[(size_t)row * 128 + cg * 4] = acc[r];
    }
}

// ---------------- GEMM 128->40 with bias (LDS-staged W, padded to 64) ----------------

__global__ __launch_bounds__(256) void gemm40_k(const float* __restrict__ X,
        const float* __restrict__ W, const float* __restrict__ bias,
        float* __restrict__ H) {
    constexpr int F_OUT = 40, F_PAD = 64;
    constexpr int RB  = 32;
    constexpr int CG  = F_PAD / 4;     // 16
    constexpr int RG  = 256 / CG;      // 16
    constexpr int RPT = RB / RG;       // 2
    __shared__ float xs[RB * 128];
    __shared__ float ws[128 * F_PAD];
    int tid = threadIdx.x;
    int row0 = blockIdx.x * RB;

    for (int idx = tid; idx < 128 * F_PAD; idx += 256) {
        int k = idx / F_PAD, c = idx - k * F_PAD;
        ws[idx] = (c < F_OUT) ? W[k * F_OUT + c] : 0.f;
    }
    int rows_in = N_NODES - row0; if (rows_in > RB) rows_in = RB;
    int limit4 = rows_in * 32;
    const float4* xg = (const float4*)(X + (size_t)row0 * 128);
    float4* xs4 = (float4*)xs;
    for (int idx = tid; idx < RB * 32; idx += 256) {
        float4 v = {0.f, 0.f, 0.f, 0.f};
        if (idx < limit4) v = xg[idx];
        xs4[idx] = v;
    }
    __syncthreads();

    int cg = tid % CG, rg = tid / CG;
    float acc[RPT][4];
    #pragma unroll
    for (int r = 0; r < RPT; r++) { acc[r][0] = acc[r][1] = acc[r][2] = acc[r][3] = 0.f; }

    #pragma unroll 4
    for (int k = 0; k < 128; k++) {
        float4 wv = *(const float4*)&ws[k * F_PAD + cg * 4];
        #pragma unroll
        for (int r = 0; r < RPT; r++) {
            float a = xs[(rg * RPT + r) * 128 + k];
            acc[r][0] = fmaf(a, wv.x, acc[r][0]);
            acc[r][1] = fmaf(a, wv.y, acc[r][1]);
            acc[r][2] = fmaf(a, wv.z, acc[r][2]);
            acc[r][3] = fmaf(a, wv.w, acc[r][3]);
        }
    }

    #pragma unroll
    for (int r = 0; r < RPT; r++) {
        int row = row0 + rg * RPT + r;
        if (row < N_NODES) {
            int cb = cg * 4;
            #pragma unroll
            for (int j = 0; j < 4; j++)
                if (cb + j < F_OUT)
                    H[(size_t)row * F_OUT + cb + j] = acc[r][j] + bias[cb + j];
        }
    }
}

// ---------------- scan ----------------

__global__ void block_sums_k(const int* __restrict__ cnt, int* bsum) {
    __shared__ int s[256];
    int b = blockIdx.x, t = threadIdx.x;
    int base = b * SCAN_B;
    int acc = 0;
    for (int j = t; j < SCAN_B; j += 256) {
        int i = base + j;
        acc += (i < N_NODES) ? cnt[i] : 0;
    }
    s[t] = acc;
    __syncthreads();
    for (int off = 128; off > 0; off >>= 1) {
        if (t < off) s[t] += s[t + off];
        __syncthreads();
    }
    if (t == 0) bsum[b] = s[0];
}

__global__ __launch_bounds__(SCAN_B) void scan_within_k(const int* __restrict__ cnt,
        const int* __restrict__ bsum, int* rowptr) {
    __shared__ int s[SCAN_B];
    __shared__ int base_s;
    int b = blockIdx.x, t = threadIdx.x;
    if (t < 64) {
        int v = (t < b) ? bsum[t] : 0;          // NB = 49 <= 64
        #pragma unroll
        for (int off = 32; off > 0; off >>= 1) v += __shfl_down(v, off, 64);
        if (t == 0) base_s = v;
    }
    int i = b * SCAN_B + t;
    int c = (i < N_NODES) ? cnt[i] : 0;
    int x = c;
    s[t] = x;
    __syncthreads();
    for (int off = 1; off < SCAN_B; off <<= 1) {
        int v = (t >= off) ? s[t - off] : 0;
        __syncthreads();
        x += v;
        s[t] = x;
        __syncthreads();
    }
    int base = base_s;
    if (i < N_NODES) rowptr[i] = base + x - c;
    if (b == NB - 1 && t == SCAN_B - 1) rowptr[N_NODES] = base + x;
}

// ---------------- scatter (no atomics): ev[rowptr[dst]+rank] = (src, raw ew) ----------------

__global__ void scatter_k(const int* __restrict__ src, const int* __restrict__ dst,
                          const float* __restrict__ ew, const int* __restrict__ rowptr,
                          const int* __restrict__ rank, int2* __restrict__ ev) {
    int e = blockIdx.x * 256 + threadIdx.x;
    if (e < N_EDGES) {
        int pos = rowptr[dst[e]] + rank[e];
        ev[pos] = make_int2(src[e], __float_as_int(ew[e]));
    }
}

// ---------------- degree from built CSR ----------------

__global__ void deg_k(const int2* __restrict__ ev, const int* __restrict__ rowptr,
                      float* dinv) {
    int i = blockIdx.x * 256 + threadIdx.x;
    if (i >= N_NODES) return;
    int e0 = rowptr[i], e1 = rowptr[i + 1];
    float s = 1.0f;                              // self-loop weight
    for (int e = e0; e < e1; e++) s += __int_as_float(ev[e].y);
    dinv[i] = rsqrtf(s);
}

// ---------------- Aggregation ----------------
// out_i = dinv_i * ( sum_e ew_e*dinv[src_e]*h[src_e] + dinv_i*h_i )  (+bias, relu)
// 4 waves/block, one node per wave; lane handles feature pair (2f,2f+1).

template<int MODE>   // 0: plain, 1: +bias +relu
__global__ __launch_bounds__(256) void agg128_k(const float* __restrict__ H,
        const int2* __restrict__ ev, const int* __restrict__ rowptr,
        const float* __restrict__ dinv, const float* __restrict__ bias,
        float* __restrict__ out) {
    int lane = threadIdx.x & 63;
    int node = __builtin_amdgcn_readfirstlane(blockIdx.x * 4 + (threadIdx.x >> 6));
    if (node >= N_NODES) return;
    const float2* __restrict__ H2 = (const float2*)H;
    float di = dinv[node];
    float2 hs = H2[(size_t)node * 64 + lane];
    float ax = di * hs.x, ay = di * hs.y;        // self term (x di at the end -> di^2)
    int e0 = rowptr[node], e1 = rowptr[node + 1];
    int e = e0;
    for (; e + 4 <= e1; e += 4) {
        int2 p0 = ev[e + 0];
        int2 p1 = ev[e + 1];
        int2 p2 = ev[e + 2];
        int2 p3 = ev[e + 3];
        float d0 = dinv[p0.x], d1 = dinv[p1.x], d2 = dinv[p2.x], d3 = dinv[p3.x];
        float2 g0 = H2[(size_t)p0.x * 64 + lane];
        float2 g1 = H2[(size_t)p1.x * 64 + lane];
        float2 g2 = H2[(size_t)p2.x * 64 + lane];
        float2 g3 = H2[(size_t)p3.x * 64 + lane];
        float v0 = __int_as_float(p0.y) * d0;
        float v1 = __int_as_float(p1.y) * d1;
        float v2 = __int_as_float(p2.y) * d2;
        float v3 = __int_as_float(p3.y) * d3;
        ax = fmaf(v0, g0.x, ax); ay = fmaf(v0, g0.y, ay);
        ax = fmaf(v1, g1.x, ax); ay = fmaf(v1, g1.y, ay);
        ax = fmaf(v2, g2.x, ax); ay = fmaf(v2, g2.y, ay);
        ax = fmaf(v3, g3.x, ax); ay = fmaf(v3, g3.y, ay);
    }
    for (; e < e1; e++) {
        int2 p = ev[e];
        float v = __int_as_float(p.y) * dinv[p.x];
        float2 g = H2[(size_t)p.x * 64 + lane];
        ax = fmaf(v, g.x, ax);
        ay = fmaf(v, g.y, ay);
    }
    ax *= di; ay *= di;
    if constexpr (MODE == 1) {
        float2 b = *(const float2*)&bias[2 * lane];
        ax = fmaxf(ax + b.x, 0.f);
        ay = fmaxf(ay + b.y, 0.f);
    }
    float2 o; o.x = ax; o.y = ay;
    *(float2*)&out[(size_t)node * 128 + 2 * lane] = o;
}

// ---------------- launch ----------------

extern "C" void kernel_launch(void* const* d_in, const int* in_sizes, int n_in,
                              void* d_out, int out_size, void* d_ws, size_t ws_size,
                              hipStream_t stream) {
    const float* x  = (const float*)d_in[0];
    const int*   ei = (const int*)d_in[1];
    const int*   src = ei;
    const int*   dst = ei + N_EDGES;
    const float* ew = (const float*)d_in[2];
    const float* W1 = (const float*)d_in[3];
    const float* b1 = (const float*)d_in[4];
    const float* W2 = (const float*)d_in[5];
    const float* b2 = (const float*)d_in[6];
    const float* W3 = (const float*)d_in[7];
    const float* b3 = (const float*)d_in[8];
    float* out = (float*)d_out;

    char* w = (char*)d_ws;
    auto alloc = [&](size_t bytes) {
        char* p = w;
        w += (bytes + 255) & ~(size_t)255;
        return p;
    };
    float* dinv   = (float*)alloc((size_t)N_NODES * 4);
    int*   rowptr = (int*)  alloc((size_t)(N_NODES + 1) * 4);
    int*   cnt    = (int*)  alloc((size_t)N_NODES * 4);
    int*   bsum   = (int*)  alloc((size_t)NB * 4);
    int*   rank   = (int*)  alloc((size_t)N_EDGES * 4);
    int2*  ev     = (int2*) alloc((size_t)N_EDGES * 8);
    float* hbuf   = (float*)alloc((size_t)N_NODES * 128 * 4);
    float* abuf   = (float*)alloc((size_t)N_NODES * 128 * 4);

    int gN = (N_NODES + 255) / 256;
    constexpr int GA = (N_NODES + 3) / 4;

    zero_k<<<gN, 256, 0, stream>>>(cnt);
    // fused: rank pass + gemm1 (x @ W1 -> hbuf)
    gemm128_k<true><<<HB + GB128, 256, 0, stream>>>(x, W1, hbuf, dst, cnt, rank);
    block_sums_k<<<NB, 256, 0, stream>>>(cnt, bsum);
    scan_within_k<<<NB, SCAN_B, 0, stream>>>(cnt, bsum, rowptr);
    scatter_k<<<HB, 256, 0, stream>>>(src, dst, ew, rowptr, rank, ev);
    deg_k<<<gN, 256, 0, stream>>>(ev, rowptr, dinv);

    agg128_k<1><<<GA, 256, 0, stream>>>(hbuf, ev, rowptr, dinv, b1, abuf);
    gemm128_k<false><<<GB128, 256, 0, stream>>>(abuf, W2, hbuf, nullptr, nullptr, nullptr);
    agg128_k<1><<<GA, 256, 0, stream>>>(hbuf, ev, rowptr, dinv, b2, abuf);
    agg128_k<0><<<GA, 256, 0, stream>>>(abuf, ev, rowptr, dinv, nullptr, hbuf);
    gemm40_k<<<GB128, 256, 0, stream>>>(hbuf, W3, b3, out);
}

// Round 5
// 359.876 us; speedup vs baseline: 1.3305x; 1.0732x over previous
//
#include <hip/hip_runtime.h>

constexpr int N_NODES = 50000;
constexpr int N_EDGES = 640000;

constexpr int NBLK  = 256;                    // edge-chunk blocks
constexpr int EPB   = N_EDGES / NBLK;         // 2500 (exact)
constexpr int NBUCK = (N_NODES + 255) / 256;  // 196 buckets of 256 dst each
constexpr int GB128 = (N_NODES + 31) / 32;    // gemm blocks (RB=32)

// ---------------- GEMM 128x128, fused (optionally) with P1 bucket histogram ----------------
// FUSE: blocks [0,NBLK) do the LDS bucket histogram; blocks [NBLK,..) do the GEMM.
// W streamed from L2 as float4; LDS = 16 KB X-tile.

template<bool FUSE_HIST>
__global__ __launch_bounds__(256) void gemm128_k(const float* __restrict__ X,
        const float* __restrict__ W, float* __restrict__ H,
        const int* __restrict__ dst, int* __restrict__ gh) {
    if constexpr (FUSE_HIST) {
        if (blockIdx.x < NBLK) {
            __shared__ int lh[256];
            int t = threadIdx.x, b = blockIdx.x;
            lh[t] = 0;
            __syncthreads();
            int e0 = b * EPB;
            for (int j = t; j < EPB; j += 256)
                atomicAdd(&lh[dst[e0 + j] >> 8], 1);
            __syncthreads();
            if (t < NBUCK) gh[b * NBUCK + t] = lh[t];
            return;
        }
    }
    int bid = FUSE_HIST ? (int)blockIdx.x - NBLK : (int)blockIdx.x;

    constexpr int RB = 32;
    __shared__ float4 xs4[RB * 32];
    int tid = threadIdx.x;
    int row0 = bid * RB;

    int rows_in = N_NODES - row0; if (rows_in > RB) rows_in = RB;
    int limit4 = rows_in * 32;
    const float4* xg = (const float4*)(X + (size_t)row0 * 128);
    for (int idx = tid; idx < RB * 32; idx += 256) {
        float4 v = {0.f, 0.f, 0.f, 0.f};
        if (idx < limit4) v = xg[idx];
        xs4[idx] = v;
    }
    __syncthreads();

    int cg = tid & 31;
    int rg = tid >> 5;
    const float4* Wg = (const float4*)W;

    float4 acc[4];
    #pragma unroll
    for (int r = 0; r < 4; r++) acc[r] = make_float4(0.f, 0.f, 0.f, 0.f);

    #pragma unroll 2
    for (int kc = 0; kc < 32; kc++) {
        float4 w0 = Wg[(4 * kc + 0) * 32 + cg];
        float4 w1 = Wg[(4 * kc + 1) * 32 + cg];
        float4 w2 = Wg[(4 * kc + 2) * 32 + cg];
        float4 w3 = Wg[(4 * kc + 3) * 32 + cg];
        #pragma unroll
        for (int r = 0; r < 4; r++) {
            float4 a = xs4[(rg * 4 + r) * 32 + kc];
            acc[r].x = fmaf(a.x, w0.x, acc[r].x);
            acc[r].y = fmaf(a.x, w0.y, acc[r].y);
            acc[r].z = fmaf(a.x, w0.z, acc[r].z);
            acc[r].w = fmaf(a.x, w0.w, acc[r].w);
            acc[r].x = fmaf(a.y, w1.x, acc[r].x);
            acc[r].y = fmaf(a.y, w1.y, acc[r].y);
            acc[r].z = fmaf(a.y, w1.z, acc[r].z);
            acc[r].w = fmaf(a.y, w1.w, acc[r].w);
            acc[r].x = fmaf(a.z, w2.x, acc[r].x);
            acc[r].y = fmaf(a.z, w2.y, acc[r].y);
            acc[r].z = fmaf(a.z, w2.z, acc[r].z);
            acc[r].w = fmaf(a.z, w2.w, acc[r].w);
            acc[r].x = fmaf(a.w, w3.x, acc[r].x);
            acc[r].y = fmaf(a.w, w3.y, acc[r].y);
            acc[r].z = fmaf(a.w, w3.z, acc[r].z);
            acc[r].w = fmaf(a.w, w3.w, acc[r].w);
        }
    }

    #pragma unroll
    for (int r = 0; r < 4; r++) {
        int row = row0 + rg * 4 + r;
        if (row < N_NODES)
            *(float4*)&H[(size_t)row * 128 + cg * 4] = acc[r];
    }
}

// ---------------- GEMM 128->40 with bias ----------------

__global__ __launch_bounds__(256) void gemm40_k(const float* __restrict__ X,
        const float* __restrict__ W, const float* __restrict__ bias,
        float* __restrict__ H) {
    constexpr int F_OUT = 40, F_PAD = 64;
    constexpr int RB  = 32;
    constexpr int CG  = F_PAD / 4;
    constexpr int RG  = 256 / CG;
    constexpr int RPT = RB / RG;
    __shared__ float xs[RB * 128];
    __shared__ float ws[128 * F_PAD];
    int tid = threadIdx.x;
    int row0 = blockIdx.x * RB;

    for (int idx = tid; idx < 128 * F_PAD; idx += 256) {
        int k = idx / F_PAD, c = idx - k * F_PAD;
        ws[idx] = (c < F_OUT) ? W[k * F_OUT + c] : 0.f;
    }
    int rows_in = N_NODES - row0; if (rows_in > RB) rows_in = RB;
    int limit4 = rows_in * 32;
    const float4* xg = (const float4*)(X + (size_t)row0 * 128);
    float4* xs4 = (float4*)xs;
    for (int idx = tid; idx < RB * 32; idx += 256) {
        float4 v = {0.f, 0.f, 0.f, 0.f};
        if (idx < limit4) v = xg[idx];
        xs4[idx] = v;
    }
    __syncthreads();

    int cg = tid % CG, rg = tid / CG;
    float acc[RPT][4];
    #pragma unroll
    for (int r = 0; r < RPT; r++) { acc[r][0] = acc[r][1] = acc[r][2] = acc[r][3] = 0.f; }

    #pragma unroll 4
    for (int k = 0; k < 128; k++) {
        float4 wv = *(const float4*)&ws[k * F_PAD + cg * 4];
        #pragma unroll
        for (int r = 0; r < RPT; r++) {
            float a = xs[(rg * RPT + r) * 128 + k];
            acc[r][0] = fmaf(a, wv.x, acc[r][0]);
            acc[r][1] = fmaf(a, wv.y, acc[r][1]);
            acc[r][2] = fmaf(a, wv.z, acc[r][2]);
            acc[r][3] = fmaf(a, wv.w, acc[r][3]);
        }
    }

    #pragma unroll
    for (int r = 0; r < RPT; r++) {
        int row = row0 + rg * RPT + r;
        if (row < N_NODES) {
            int cb = cg * 4;
            #pragma unroll
            for (int j = 0; j < 4; j++)
                if (cb + j < F_OUT)
                    H[(size_t)row * F_OUT + cb + j] = acc[r][j] + bias[cb + j];
        }
    }
}

// ---------------- sort scans ----------------
// gh layout: gh[block * NBUCK + bucket]. scan1: one block per bucket,
// exclusive scan over the 256 chunk-blocks; writes per-bucket totals.

__global__ __launch_bounds__(256) void scan1_k(int* __restrict__ gh, int* __restrict__ total) {
    __shared__ int s[256];
    int t = threadIdx.x, b = blockIdx.x;
    int v = gh[t * NBUCK + b];
    s[t] = v;
    __syncthreads();
    int x = v;
    for (int off = 1; off < 256; off <<= 1) {
        int u = (t >= off) ? s[t - off] : 0;
        __syncthreads();
        x += u; s[t] = x;
        __syncthreads();
    }
    gh[t * NBUCK + b] = x - v;            // exclusive within bucket
    if (t == 255) total[b] = x;
}

// scan2: bucket bases (exclusive scan of 196 totals); bbase[NBUCK] = N_EDGES.

__global__ __launch_bounds__(256) void scan2_k(const int* __restrict__ total,
                                               int* __restrict__ bbase) {
    __shared__ int s[256];
    int t = threadIdx.x;
    int v = (t < NBUCK) ? total[t] : 0;
    s[t] = v;
    __syncthreads();
    int x = v;
    for (int off = 1; off < 256; off <<= 1) {
        int u = (t >= off) ? s[t - off] : 0;
        __syncthreads();
        x += u; s[t] = x;
        __syncthreads();
    }
    if (t <= NBUCK) bbase[t] = x - v;
}

// ---------------- bucket scatter (LDS cursors, no global atomics) ----------------
// record: (src | dst<<16, ew-bits) — both ids < 65536.

__global__ __launch_bounds__(256) void bucket_k(const int* __restrict__ src,
        const int* __restrict__ dst, const float* __restrict__ ew,
        const int* __restrict__ gh, const int* __restrict__ bbase,
        int2* __restrict__ bkt) {
    __shared__ int cur[256];
    int t = threadIdx.x, b = blockIdx.x;
    if (t < NBUCK) cur[t] = bbase[t] + gh[b * NBUCK + t];
    __syncthreads();
    int e0 = b * EPB;
    for (int j = t; j < EPB; j += 256) {
        int d = dst[e0 + j];
        int pos = atomicAdd(&cur[d >> 8], 1);
        bkt[pos] = make_int2(src[e0 + j] | (d << 16), __float_as_int(ew[e0 + j]));
    }
}

// ---------------- finalize: per-bucket dst sort + rowptr + dinv ----------------

__global__ __launch_bounds__(256) void final_k(const int2* __restrict__ bkt,
        const int* __restrict__ bbase, int2* __restrict__ ev,
        int* __restrict__ rowptr, float* __restrict__ dinv) {
    __shared__ int   cnt[256];
    __shared__ float wsum[256];
    __shared__ int   s[256];
    int t = threadIdx.x, b = blockIdx.x;
    int base = bbase[b], cntb = bbase[b + 1] - base;
    cnt[t] = 0; wsum[t] = 0.f;
    __syncthreads();
    for (int j = t; j < cntb; j += 256) {
        int2 r = bkt[base + j];
        int bin = (r.x >> 16) & 255;
        atomicAdd(&cnt[bin], 1);
        atomicAdd(&wsum[bin], __int_as_float(r.y));
    }
    __syncthreads();
    int v = cnt[t];
    s[t] = v;
    __syncthreads();
    int x = v;
    for (int off = 1; off < 256; off <<= 1) {
        int u = (t >= off) ? s[t - off] : 0;
        __syncthreads();
        x += u; s[t] = x;
        __syncthreads();
    }
    int off_t = x - v;                    // exclusive within bucket
    int nd = b * 256 + t;
    if (nd < N_NODES) {
        rowptr[nd] = base + off_t;
        dinv[nd] = rsqrtf(1.0f + wsum[t]);
    }
    if (b == 0 && t == 0) rowptr[N_NODES] = N_EDGES;
    s[t] = off_t;                         // cursors
    __syncthreads();
    for (int j = t; j < cntb; j += 256) {
        int2 r = bkt[base + j];
        int bin = (r.x >> 16) & 255;
        int p = atomicAdd(&s[bin], 1);
        ev[base + p] = make_int2(r.x & 0xFFFF, r.y);
    }
}

// ---------------- Aggregation ----------------
// out_i = dinv_i * ( sum_e ew_e*dinv[src_e]*h[src_e] + dinv_i*h_i )  (+bias, relu)

template<int MODE>   // 0: plain, 1: +bias +relu
__global__ __launch_bounds__(256) void agg128_k(const float* __restrict__ H,
        const int2* __restrict__ ev, const int* __restrict__ rowptr,
        const float* __restrict__ dinv, const float* __restrict__ bias,
        float* __restrict__ out) {
    int lane = threadIdx.x & 63;
    int node = __builtin_amdgcn_readfirstlane(blockIdx.x * 4 + (threadIdx.x >> 6));
    if (node >= N_NODES) return;
    const float2* __restrict__ H2 = (const float2*)H;
    float di = dinv[node];
    float2 hs = H2[(size_t)node * 64 + lane];
    float ax = di * hs.x, ay = di * hs.y;
    int e0 = rowptr[node], e1 = rowptr[node + 1];
    int e = e0;
    for (; e + 4 <= e1; e += 4) {
        int2 p0 = ev[e + 0];
        int2 p1 = ev[e + 1];
        int2 p2 = ev[e + 2];
        int2 p3 = ev[e + 3];
        float d0 = dinv[p0.x], d1 = dinv[p1.x], d2 = dinv[p2.x], d3 = dinv[p3.x];
        float2 g0 = H2[(size_t)p0.x * 64 + lane];
        float2 g1 = H2[(size_t)p1.x * 64 + lane];
        float2 g2 = H2[(size_t)p2.x * 64 + lane];
        float2 g3 = H2[(size_t)p3.x * 64 + lane];
        float v0 = __int_as_float(p0.y) * d0;
        float v1 = __int_as_float(p1.y) * d1;
        float v2 = __int_as_float(p2.y) * d2;
        float v3 = __int_as_float(p3.y) * d3;
        ax = fmaf(v0, g0.x, ax); ay = fmaf(v0, g0.y, ay);
        ax = fmaf(v1, g1.x, ax); ay = fmaf(v1, g1.y, ay);
        ax = fmaf(v2, g2.x, ax); ay = fmaf(v2, g2.y, ay);
        ax = fmaf(v3, g3.x, ax); ay = fmaf(v3, g3.y, ay);
    }
    for (; e < e1; e++) {
        int2 p = ev[e];
        float v = __int_as_float(p.y) * dinv[p.x];
        float2 g = H2[(size_t)p.x * 64 + lane];
        ax = fmaf(v, g.x, ax);
        ay = fmaf(v, g.y, ay);
    }
    ax *= di; ay *= di;
    if constexpr (MODE == 1) {
        float2 b = *(const float2*)&bias[2 * lane];
        ax = fmaxf(ax + b.x, 0.f);
        ay = fmaxf(ay + b.y, 0.f);
    }
    float2 o; o.x = ax; o.y = ay;
    *(float2*)&out[(size_t)node * 128 + 2 * lane] = o;
}

// ---------------- launch ----------------

extern "C" void kernel_launch(void* const* d_in, const int* in_sizes, int n_in,
                              void* d_out, int out_size, void* d_ws, size_t ws_size,
                              hipStream_t stream) {
    const float* x  = (const float*)d_in[0];
    const int*   ei = (const int*)d_in[1];
    const int*   src = ei;
    const int*   dst = ei + N_EDGES;
    const float* ew = (const float*)d_in[2];
    const float* W1 = (const float*)d_in[3];
    const float* b1 = (const float*)d_in[4];
    const float* W2 = (const float*)d_in[5];
    const float* b2 = (const float*)d_in[6];
    const float* W3 = (const float*)d_in[7];
    const float* b3 = (const float*)d_in[8];
    float* out = (float*)d_out;

    char* w = (char*)d_ws;
    auto alloc = [&](size_t bytes) {
        char* p = w;
        w += (bytes + 255) & ~(size_t)255;
        return p;
    };
    float* dinv   = (float*)alloc((size_t)N_NODES * 4);
    int*   rowptr = (int*)  alloc((size_t)(N_NODES + 1) * 4);
    int*   gh     = (int*)  alloc((size_t)NBLK * NBUCK * 4);
    int*   total  = (int*)  alloc((size_t)NBUCK * 4);
    int*   bbase  = (int*)  alloc((size_t)(NBUCK + 1) * 4);
    int2*  bkt    = (int2*) alloc((size_t)N_EDGES * 8);
    int2*  ev     = (int2*) alloc((size_t)N_EDGES * 8);
    float* hbuf   = (float*)alloc((size_t)N_NODES * 128 * 4);
    float* abuf   = (float*)alloc((size_t)N_NODES * 128 * 4);

    constexpr int GA = (N_NODES + 3) / 4;

    // fused: P1 bucket histogram + gemm1 (x @ W1 -> hbuf)
    gemm128_k<true><<<NBLK + GB128, 256, 0, stream>>>(x, W1, hbuf, dst, gh);
    scan1_k<<<NBUCK, 256, 0, stream>>>(gh, total);
    scan2_k<<<1, 256, 0, stream>>>(total, bbase);
    bucket_k<<<NBLK, 256, 0, stream>>>(src, dst, ew, gh, bbase, bkt);
    final_k<<<NBUCK, 256, 0, stream>>>(bkt, bbase, ev, rowptr, dinv);

    agg128_k<1><<<GA, 256, 0, stream>>>(hbuf, ev, rowptr, dinv, b1, abuf);
    gemm128_k<false><<<GB128, 256, 0, stream>>>(abuf, W2, hbuf, nullptr, nullptr);
    agg128_k<1><<<GA, 256, 0, stream>>>(hbuf, ev, rowptr, dinv, b2, abuf);
    agg128_k<0><<<GA, 256, 0, stream>>>(abuf, ev, rowptr, dinv, nullptr, hbuf);
    gemm40_k<<<GB128, 256, 0, stream>>>(hbuf, W3, b3, out);
}

// Round 6
// 293.145 us; speedup vs baseline: 1.6334x; 1.2276x over previous
//
#include <hip/hip_runtime.h>
#include <hip/hip_fp16.h>

constexpr int N_NODES = 50000;
constexpr int N_EDGES = 640000;

constexpr int NBLK  = 256;                    // edge-chunk blocks
constexpr int EPB   = N_EDGES / NBLK;         // 2500 (exact)
constexpr int NBUCK = (N_NODES + 255) / 256;  // 196 buckets of 256 dst each
constexpr int GB128 = (N_NODES + 31) / 32;    // gemm blocks (RB=32)

// ---------------- GEMM 128x128 -> half H, optionally fused with P1 histogram ----------------

template<typename TIN, bool FUSE_HIST>
__global__ __launch_bounds__(256) void gemm128_k(const TIN* __restrict__ X,
        const float* __restrict__ W, __half* __restrict__ H,
        const int* __restrict__ dst, int* __restrict__ gh) {
    if constexpr (FUSE_HIST) {
        if (blockIdx.x < NBLK) {
            __shared__ int lh[256];
            int t = threadIdx.x, b = blockIdx.x;
            lh[t] = 0;
            __syncthreads();
            int e0 = b * EPB;
            for (int j = t; j < EPB; j += 256)
                atomicAdd(&lh[dst[e0 + j] >> 8], 1);
            __syncthreads();
            if (t < NBUCK) gh[b * NBUCK + t] = lh[t];
            return;
        }
    }
    int bid = FUSE_HIST ? (int)blockIdx.x - NBLK : (int)blockIdx.x;

    constexpr int RB = 32;
    __shared__ float4 xs4[RB * 32];
    int tid = threadIdx.x;
    int row0 = bid * RB;

    int rows_in = N_NODES - row0; if (rows_in > RB) rows_in = RB;
    int limit4 = rows_in * 32;                 // groups of 4 elements
    for (int idx = tid; idx < RB * 32; idx += 256) {
        float4 v = {0.f, 0.f, 0.f, 0.f};
        if (idx < limit4) {
            if constexpr (sizeof(TIN) == 4) {
                v = ((const float4*)(X + (size_t)row0 * 128))[idx];
            } else {
                int2 raw = ((const int2*)(X + (size_t)row0 * 128))[idx];
                __half2 a = *(__half2*)&raw.x;
                __half2 bq = *(__half2*)&raw.y;
                float2 fa = __half22float2(a), fb = __half22float2(bq);
                v = make_float4(fa.x, fa.y, fb.x, fb.y);
            }
        }
        xs4[idx] = v;
    }
    __syncthreads();

    int cg = tid & 31;
    int rg = tid >> 5;
    const float4* Wg = (const float4*)W;

    float4 acc[4];
    #pragma unroll
    for (int r = 0; r < 4; r++) acc[r] = make_float4(0.f, 0.f, 0.f, 0.f);

    #pragma unroll 2
    for (int kc = 0; kc < 32; kc++) {
        float4 w0 = Wg[(4 * kc + 0) * 32 + cg];
        float4 w1 = Wg[(4 * kc + 1) * 32 + cg];
        float4 w2 = Wg[(4 * kc + 2) * 32 + cg];
        float4 w3 = Wg[(4 * kc + 3) * 32 + cg];
        #pragma unroll
        for (int r = 0; r < 4; r++) {
            float4 a = xs4[(rg * 4 + r) * 32 + kc];
            acc[r].x = fmaf(a.x, w0.x, acc[r].x);
            acc[r].y = fmaf(a.x, w0.y, acc[r].y);
            acc[r].z = fmaf(a.x, w0.z, acc[r].z);
            acc[r].w = fmaf(a.x, w0.w, acc[r].w);
            acc[r].x = fmaf(a.y, w1.x, acc[r].x);
            acc[r].y = fmaf(a.y, w1.y, acc[r].y);
            acc[r].z = fmaf(a.y, w1.z, acc[r].z);
            acc[r].w = fmaf(a.y, w1.w, acc[r].w);
            acc[r].x = fmaf(a.z, w2.x, acc[r].x);
            acc[r].y = fmaf(a.z, w2.y, acc[r].y);
            acc[r].z = fmaf(a.z, w2.z, acc[r].z);
            acc[r].w = fmaf(a.z, w2.w, acc[r].w);
            acc[r].x = fmaf(a.w, w3.x, acc[r].x);
            acc[r].y = fmaf(a.w, w3.y, acc[r].y);
            acc[r].z = fmaf(a.w, w3.z, acc[r].z);
            acc[r].w = fmaf(a.w, w3.w, acc[r].w);
        }
    }

    #pragma unroll
    for (int r = 0; r < 4; r++) {
        int row = row0 + rg * 4 + r;
        if (row < N_NODES) {
            __half2 h0 = __float22half2_rn(make_float2(acc[r].x, acc[r].y));
            __half2 h1 = __float22half2_rn(make_float2(acc[r].z, acc[r].w));
            int2 o; o.x = *(int*)&h0; o.y = *(int*)&h1;
            *(int2*)&H[(size_t)row * 128 + cg * 4] = o;
        }
    }
}

// ---------------- GEMM 128->40, half in, half out, NO bias (bias after agg) ----------------

__global__ __launch_bounds__(256) void gemm40_k(const __half* __restrict__ X,
        const float* __restrict__ W, __half* __restrict__ Y) {
    constexpr int F_OUT = 40, F_PAD = 64;
    constexpr int RB  = 32;
    constexpr int CG  = F_PAD / 4;     // 16
    constexpr int RG  = 256 / CG;      // 16
    constexpr int RPT = RB / RG;       // 2
    __shared__ float xs[RB * 128];
    __shared__ float ws[128 * F_PAD];
    int tid = threadIdx.x;
    int row0 = blockIdx.x * RB;

    for (int idx = tid; idx < 128 * F_PAD; idx += 256) {
        int k = idx / F_PAD, c = idx - k * F_PAD;
        ws[idx] = (c < F_OUT) ? W[k * F_OUT + c] : 0.f;
    }
    int rows_in = N_NODES - row0; if (rows_in > RB) rows_in = RB;
    int limit4 = rows_in * 32;
    float4* xs4 = (float4*)xs;
    for (int idx = tid; idx < RB * 32; idx += 256) {
        float4 v = {0.f, 0.f, 0.f, 0.f};
        if (idx < limit4) {
            int2 raw = ((const int2*)(X + (size_t)row0 * 128))[idx];
            __half2 a = *(__half2*)&raw.x;
            __half2 bq = *(__half2*)&raw.y;
            float2 fa = __half22float2(a), fb = __half22float2(bq);
            v = make_float4(fa.x, fa.y, fb.x, fb.y);
        }
        xs4[idx] = v;
    }
    __syncthreads();

    int cg = tid % CG, rg = tid / CG;
    float acc[RPT][4];
    #pragma unroll
    for (int r = 0; r < RPT; r++) { acc[r][0] = acc[r][1] = acc[r][2] = acc[r][3] = 0.f; }

    #pragma unroll 4
    for (int k = 0; k < 128; k++) {
        float4 wv = *(const float4*)&ws[k * F_PAD + cg * 4];
        #pragma unroll
        for (int r = 0; r < RPT; r++) {
            float a = xs[(rg * RPT + r) * 128 + k];
            acc[r][0] = fmaf(a, wv.x, acc[r][0]);
            acc[r][1] = fmaf(a, wv.y, acc[r][1]);
            acc[r][2] = fmaf(a, wv.z, acc[r][2]);
            acc[r][3] = fmaf(a, wv.w, acc[r][3]);
        }
    }

    #pragma unroll
    for (int r = 0; r < RPT; r++) {
        int row = row0 + rg * RPT + r;
        int cb = cg * 4;
        if (row < N_NODES && cb < F_OUT) {
            __half2 h0 = __float22half2_rn(make_float2(acc[r][0], acc[r][1]));
            __half2 h1 = __float22half2_rn(make_float2(acc[r][2], acc[r][3]));
            int2 o; o.x = *(int*)&h0; o.y = *(int*)&h1;
            *(int2*)&Y[(size_t)row * F_OUT + cb] = o;
        }
    }
}

// ---------------- sort scans ----------------

__global__ __launch_bounds__(256) void scan1_k(int* __restrict__ gh, int* __restrict__ total) {
    __shared__ int s[256];
    int t = threadIdx.x, b = blockIdx.x;
    int v = gh[t * NBUCK + b];
    s[t] = v;
    __syncthreads();
    int x = v;
    for (int off = 1; off < 256; off <<= 1) {
        int u = (t >= off) ? s[t - off] : 0;
        __syncthreads();
        x += u; s[t] = x;
        __syncthreads();
    }
    gh[t * NBUCK + b] = x - v;            // exclusive within bucket
    if (t == 255) total[b] = x;
}

__global__ __launch_bounds__(256) void scan2_k(const int* __restrict__ total,
                                               int* __restrict__ bbase) {
    __shared__ int s[256];
    int t = threadIdx.x;
    int v = (t < NBUCK) ? total[t] : 0;
    s[t] = v;
    __syncthreads();
    int x = v;
    for (int off = 1; off < 256; off <<= 1) {
        int u = (t >= off) ? s[t - off] : 0;
        __syncthreads();
        x += u; s[t] = x;
        __syncthreads();
    }
    if (t <= NBUCK) bbase[t] = x - v;
}

// ---------------- bucket scatter (LDS cursors, no global atomics) ----------------

__global__ __launch_bounds__(256) void bucket_k(const int* __restrict__ src,
        const int* __restrict__ dst, const float* __restrict__ ew,
        const int* __restrict__ gh, const int* __restrict__ bbase,
        int2* __restrict__ bkt) {
    __shared__ int cur[256];
    int t = threadIdx.x, b = blockIdx.x;
    if (t < NBUCK) cur[t] = bbase[t] + gh[b * NBUCK + t];
    __syncthreads();
    int e0 = b * EPB;
    for (int j = t; j < EPB; j += 256) {
        int d = dst[e0 + j];
        int pos = atomicAdd(&cur[d >> 8], 1);
        bkt[pos] = make_int2(src[e0 + j] | (d << 16), __float_as_int(ew[e0 + j]));
    }
}

// ---------------- finalize: per-bucket dst sort + rowptr + dinv ----------------

__global__ __launch_bounds__(256) void final_k(const int2* __restrict__ bkt,
        const int* __restrict__ bbase, int2* __restrict__ ev,
        int* __restrict__ rowptr, float* __restrict__ dinv) {
    __shared__ int   cnt[256];
    __shared__ float wsum[256];
    __shared__ int   s[256];
    int t = threadIdx.x, b = blockIdx.x;
    int base = bbase[b], cntb = bbase[b + 1] - base;
    cnt[t] = 0; wsum[t] = 0.f;
    __syncthreads();
    for (int j = t; j < cntb; j += 256) {
        int2 r = bkt[base + j];
        int bin = (r.x >> 16) & 255;
        atomicAdd(&cnt[bin], 1);
        atomicAdd(&wsum[bin], __int_as_float(r.y));
    }
    __syncthreads();
    int v = cnt[t];
    s[t] = v;
    __syncthreads();
    int x = v;
    for (int off = 1; off < 256; off <<= 1) {
        int u = (t >= off) ? s[t - off] : 0;
        __syncthreads();
        x += u; s[t] = x;
        __syncthreads();
    }
    int off_t = x - v;
    int nd = b * 256 + t;
    if (nd < N_NODES) {
        rowptr[nd] = base + off_t;
        dinv[nd] = rsqrtf(1.0f + wsum[t]);
    }
    if (b == 0 && t == 0) rowptr[N_NODES] = N_EDGES;
    s[t] = off_t;
    __syncthreads();
    for (int j = t; j < cntb; j += 256) {
        int2 r = bkt[base + j];
        int bin = (r.x >> 16) & 255;
        int p = atomicAdd(&s[bin], 1);
        ev[base + p] = make_int2(r.x & 0xFFFF, r.y);
    }
}

// ---------------- Aggregation, 128 half features ----------------
// out_i = relu( dinv_i*( sum_e ew*dinv[src]*h[src] + dinv_i*h_i ) + bias ), half out

__global__ __launch_bounds__(256) void agg128_k(const __half* __restrict__ H,
        const int2* __restrict__ ev, const int* __restrict__ rowptr,
        const float* __restrict__ dinv, const float* __restrict__ bias,
        __half* __restrict__ out) {
    int lane = threadIdx.x & 63;
    int node = __builtin_amdgcn_readfirstlane(blockIdx.x * 4 + (threadIdx.x >> 6));
    if (node >= N_NODES) return;
    const __half2* __restrict__ H2 = (const __half2*)H;
    float di = dinv[node];
    float2 hs = __half22float2(H2[(size_t)node * 64 + lane]);
    float ax = di * hs.x, ay = di * hs.y;
    int e0 = rowptr[node], e1 = rowptr[node + 1];
    int e = e0;
    for (; e + 4 <= e1; e += 4) {
        int2 p0 = ev[e + 0];
        int2 p1 = ev[e + 1];
        int2 p2 = ev[e + 2];
        int2 p3 = ev[e + 3];
        float d0 = dinv[p0.x], d1 = dinv[p1.x], d2 = dinv[p2.x], d3 = dinv[p3.x];
        float2 g0 = __half22float2(H2[(size_t)p0.x * 64 + lane]);
        float2 g1 = __half22float2(H2[(size_t)p1.x * 64 + lane]);
        float2 g2 = __half22float2(H2[(size_t)p2.x * 64 + lane]);
        float2 g3 = __half22float2(H2[(size_t)p3.x * 64 + lane]);
        float v0 = __int_as_float(p0.y) * d0;
        float v1 = __int_as_float(p1.y) * d1;
        float v2 = __int_as_float(p2.y) * d2;
        float v3 = __int_as_float(p3.y) * d3;
        ax = fmaf(v0, g0.x, ax); ay = fmaf(v0, g0.y, ay);
        ax = fmaf(v1, g1.x, ax); ay = fmaf(v1, g1.y, ay);
        ax = fmaf(v2, g2.x, ax); ay = fmaf(v2, g2.y, ay);
        ax = fmaf(v3, g3.x, ax); ay = fmaf(v3, g3.y, ay);
    }
    for (; e < e1; e++) {
        int2 p = ev[e];
        float v = __int_as_float(p.y) * dinv[p.x];
        float2 g = __half22float2(H2[(size_t)p.x * 64 + lane]);
        ax = fmaf(v, g.x, ax);
        ay = fmaf(v, g.y, ay);
    }
    float2 b = *(const float2*)&bias[2 * lane];
    ax = fmaxf(fmaf(ax, di, b.x), 0.f);
    ay = fmaxf(fmaf(ay, di, b.y), 0.f);
    ((__half2*)out)[(size_t)node * 64 + lane] = __float22half2_rn(make_float2(ax, ay));
}

// ---------------- Aggregation, 40 half features -> fp32 out with bias ----------------

__global__ __launch_bounds__(256) void agg40_k(const __half* __restrict__ Y,
        const int2* __restrict__ ev, const int* __restrict__ rowptr,
        const float* __restrict__ dinv, const float* __restrict__ bias,
        float* __restrict__ out) {
    int lane = threadIdx.x & 63;
    int node = __builtin_amdgcn_readfirstlane(blockIdx.x * 4 + (threadIdx.x >> 6));
    if (node >= N_NODES) return;
    const __half2* __restrict__ Y2 = (const __half2*)Y;
    int f = (lane < 20) ? lane : 0;            // feature pair index
    float di = dinv[node];
    float2 ys = __half22float2(Y2[(size_t)node * 20 + f]);
    float ax = di * ys.x, ay = di * ys.y;
    int e0 = rowptr[node], e1 = rowptr[node + 1];
    int e = e0;
    for (; e + 4 <= e1; e += 4) {
        int2 p0 = ev[e + 0];
        int2 p1 = ev[e + 1];
        int2 p2 = ev[e + 2];
        int2 p3 = ev[e + 3];
        float d0 = dinv[p0.x], d1 = dinv[p1.x], d2 = dinv[p2.x], d3 = dinv[p3.x];
        float2 g0 = __half22float2(Y2[(size_t)p0.x * 20 + f]);
        float2 g1 = __half22float2(Y2[(size_t)p1.x * 20 + f]);
        float2 g2 = __half22float2(Y2[(size_t)p2.x * 20 + f]);
        float2 g3 = __half22float2(Y2[(size_t)p3.x * 20 + f]);
        float v0 = __int_as_float(p0.y) * d0;
        float v1 = __int_as_float(p1.y) * d1;
        float v2 = __int_as_float(p2.y) * d2;
        float v3 = __int_as_float(p3.y) * d3;
        ax = fmaf(v0, g0.x, ax); ay = fmaf(v0, g0.y, ay);
        ax = fmaf(v1, g1.x, ax); ay = fmaf(v1, g1.y, ay);
        ax = fmaf(v2, g2.x, ax); ay = fmaf(v2, g2.y, ay);
        ax = fmaf(v3, g3.x, ax); ay = fmaf(v3, g3.y, ay);
    }
    for (; e < e1; e++) {
        int2 p = ev[e];
        float v = __int_as_float(p.y) * dinv[p.x];
        float2 g = __half22float2(Y2[(size_t)p.x * 20 + f]);
        ax = fmaf(v, g.x, ax);
        ay = fmaf(v, g.y, ay);
    }
    if (lane < 20) {
        float2 b = *(const float2*)&bias[2 * lane];
        float2 o;
        o.x = fmaf(ax, di, b.x);
        o.y = fmaf(ay, di, b.y);
        *(float2*)&out[(size_t)node * 40 + 2 * lane] = o;
    }
}

// ---------------- launch ----------------

extern "C" void kernel_launch(void* const* d_in, const int* in_sizes, int n_in,
                              void* d_out, int out_size, void* d_ws, size_t ws_size,
                              hipStream_t stream) {
    const float* x  = (const float*)d_in[0];
    const int*   ei = (const int*)d_in[1];
    const int*   src = ei;
    const int*   dst = ei + N_EDGES;
    const float* ew = (const float*)d_in[2];
    const float* W1 = (const float*)d_in[3];
    const float* b1 = (const float*)d_in[4];
    const float* W2 = (const float*)d_in[5];
    const float* b2 = (const float*)d_in[6];
    const float* W3 = (const float*)d_in[7];
    const float* b3 = (const float*)d_in[8];
    float* out = (float*)d_out;

    char* w = (char*)d_ws;
    auto alloc = [&](size_t bytes) {
        char* p = w;
        w += (bytes + 255) & ~(size_t)255;
        return p;
    };
    float*  dinv   = (float*) alloc((size_t)N_NODES * 4);
    int*    rowptr = (int*)   alloc((size_t)(N_NODES + 1) * 4);
    int*    gh     = (int*)   alloc((size_t)NBLK * NBUCK * 4);
    int*    total  = (int*)   alloc((size_t)NBUCK * 4);
    int*    bbase  = (int*)   alloc((size_t)(NBUCK + 1) * 4);
    int2*   bkt    = (int2*)  alloc((size_t)N_EDGES * 8);
    int2*   ev     = (int2*)  alloc((size_t)N_EDGES * 8);
    __half* hbuf   = (__half*)alloc((size_t)N_NODES * 128 * 2);
    __half* abuf   = (__half*)alloc((size_t)N_NODES * 128 * 2);
    __half* ybuf   = (__half*)alloc((size_t)N_NODES * 40 * 2);

    constexpr int GA = (N_NODES + 3) / 4;

    // fused: P1 bucket histogram + gemm1 (x @ W1 -> hbuf half)
    gemm128_k<float, true><<<NBLK + GB128, 256, 0, stream>>>(x, W1, hbuf, dst, gh);
    scan1_k<<<NBUCK, 256, 0, stream>>>(gh, total);
    scan2_k<<<1, 256, 0, stream>>>(total, bbase);
    bucket_k<<<NBLK, 256, 0, stream>>>(src, dst, ew, gh, bbase, bkt);
    final_k<<<NBUCK, 256, 0, stream>>>(bkt, bbase, ev, rowptr, dinv);

    agg128_k<<<GA, 256, 0, stream>>>(hbuf, ev, rowptr, dinv, b1, abuf);
    gemm128_k<__half, false><<<GB128, 256, 0, stream>>>(abuf, W2, hbuf, nullptr, nullptr);
    agg128_k<<<GA, 256, 0, stream>>>(hbuf, ev, rowptr, dinv, b2, abuf);
    gemm40_k<<<GB128, 256, 0, stream>>>(abuf, W3, ybuf);
    agg40_k<<<GA, 256, 0, stream>>>(ybuf, ev, rowptr, dinv, b3, out);
}

// Round 7
// 251.880 us; speedup vs baseline: 1.9010x; 1.1638x over previous
//
#include <hip/hip_runtime.h>
#include <hip/hip_fp16.h>

constexpr int N_NODES = 50000;
constexpr int N_EDGES = 640000;

constexpr int NBLK  = 256;                    // edge-chunk blocks
constexpr int EPB   = N_EDGES / NBLK;         // 2500 (exact)
constexpr int NBUCK = (N_NODES + 255) / 256;  // 196 buckets of 256 dst each
constexpr int GBM   = (N_NODES + 63) / 64;    // mfma-gemm blocks (64 rows each)

typedef _Float16 half8  __attribute__((ext_vector_type(8)));
typedef _Float16 half4v __attribute__((ext_vector_type(4)));
typedef float    floatx4 __attribute__((ext_vector_type(4)));

// ---------------- W -> W^T fp16 conversion (one-time, tiny) ----------------

__global__ void wconv_k(const float* __restrict__ W1, const float* __restrict__ W2,
                        const float* __restrict__ W3, _Float16* __restrict__ Wt1,
                        _Float16* __restrict__ Wt2, _Float16* __restrict__ Wt3) {
    int i = blockIdx.x * 256 + threadIdx.x;
    if (i < 16384) {
        int n = i >> 7, k = i & 127;
        Wt1[n * 128 + k] = (_Float16)W1[k * 128 + n];
    } else if (i < 32768) {
        int j = i - 16384; int n = j >> 7, k = j & 127;
        Wt2[n * 128 + k] = (_Float16)W2[k * 128 + n];
    } else if (i < 32768 + 6144) {
        int j = i - 32768; int n = j >> 7, k = j & 127;
        Wt3[n * 128 + k] = (_Float16)((n < 40) ? W3[k * 40 + n] : 0.f);
    }
}

// ---------------- MFMA GEMM: H[N,F_OUT] = X[N,128] @ W, fp16 in/out, fp32 acc ----------------
// 64 rows/block, 4 waves, each wave 16 rows x F_OUT cols via 16x16x32 f16 MFMA.
// A from LDS (pad-136 rows, ds_read_b128); B from global Wt[n][k] (L1-resident).
// FUSE_HIST: blocks [0,NBLK) do the LDS bucket histogram instead.

template<typename TIN, int F_OUT, int NT, bool FUSE_HIST>
__global__ __launch_bounds__(256) void gemm_mfma_k(const TIN* __restrict__ X,
        const _Float16* __restrict__ Wt, __half* __restrict__ H,
        const int* __restrict__ dst, int* __restrict__ gh) {
    if constexpr (FUSE_HIST) {
        if (blockIdx.x < NBLK) {
            __shared__ int lh[256];
            int t = threadIdx.x, b = blockIdx.x;
            lh[t] = 0;
            __syncthreads();
            int e0 = b * EPB;
            for (int j = t; j < EPB; j += 256)
                atomicAdd(&lh[dst[e0 + j] >> 8], 1);
            __syncthreads();
            if (t < NBUCK) gh[b * NBUCK + t] = lh[t];
            return;
        }
    }
    int bid = FUSE_HIST ? (int)blockIdx.x - NBLK : (int)blockIdx.x;

    __shared__ _Float16 Xs[64 * 136];      // 64 rows, stride 136 (16B-aligned pad)
    int tid = threadIdx.x;
    int row0 = bid * 64;

    if constexpr (sizeof(TIN) == 4) {      // fp32 input -> convert
        for (int idx = tid; idx < 2048; idx += 256) {
            int r = idx >> 5, c4 = idx & 31;
            float4 v = {0.f, 0.f, 0.f, 0.f};
            if (row0 + r < N_NODES)
                v = *(const float4*)((const float*)X + (size_t)(row0 + r) * 128 + c4 * 4);
            half4v h;
            h[0] = (_Float16)v.x; h[1] = (_Float16)v.y;
            h[2] = (_Float16)v.z; h[3] = (_Float16)v.w;
            *(half4v*)&Xs[r * 136 + c4 * 4] = h;
        }
    } else {                               // fp16 input -> raw copy
        for (int idx = tid; idx < 1024; idx += 256) {
            int r = idx >> 4, c8 = idx & 15;
            int4 v = {0, 0, 0, 0};
            if (row0 + r < N_NODES)
                v = *(const int4*)((const __half*)X + (size_t)(row0 + r) * 128 + c8 * 8);
            *(int4*)&Xs[r * 136 + c8 * 8] = v;
        }
    }
    __syncthreads();

    int lane = tid & 63;
    int wv   = tid >> 6;                   // wave 0..3 -> rows wv*16..+15
    int m    = lane & 15;
    int q    = lane >> 4;

    half8 af[4];
    #pragma unroll
    for (int kt = 0; kt < 4; kt++)
        af[kt] = *(const half8*)&Xs[(wv * 16 + m) * 136 + kt * 32 + q * 8];

    floatx4 acc[NT];
    #pragma unroll
    for (int nt = 0; nt < NT; nt++) { acc[nt][0] = 0.f; acc[nt][1] = 0.f; acc[nt][2] = 0.f; acc[nt][3] = 0.f; }

    #pragma unroll
    for (int nt = 0; nt < NT; nt++) {
        const _Float16* wp = Wt + (size_t)(nt * 16 + m) * 128 + q * 8;
        half8 b0 = *(const half8*)(wp);
        half8 b1 = *(const half8*)(wp + 32);
        half8 b2 = *(const half8*)(wp + 64);
        half8 b3 = *(const half8*)(wp + 96);
        acc[nt] = __builtin_amdgcn_mfma_f32_16x16x32_f16(af[0], b0, acc[nt], 0, 0, 0);
        acc[nt] = __builtin_amdgcn_mfma_f32_16x16x32_f16(af[1], b1, acc[nt], 0, 0, 0);
        acc[nt] = __builtin_amdgcn_mfma_f32_16x16x32_f16(af[2], b2, acc[nt], 0, 0, 0);
        acc[nt] = __builtin_amdgcn_mfma_f32_16x16x32_f16(af[3], b3, acc[nt], 0, 0, 0);
    }

    // C -> own wave's LDS region (rows wv*16..+15 only; no cross-wave hazard)
    #pragma unroll
    for (int nt = 0; nt < NT; nt++) {
        #pragma unroll
        for (int r = 0; r < 4; r++)
            Xs[(wv * 16 + q * 4 + r) * 136 + nt * 16 + m] = (_Float16)acc[nt][r];
    }

    // coalesced copy-out of own region
    if constexpr (F_OUT == 128) {
        for (int g = lane; g < 256; g += 64) {
            int r = g >> 4, c8 = g & 15;
            int row = row0 + wv * 16 + r;
            if (row < N_NODES)
                *(int4*)((__half*)H + (size_t)row * 128 + c8 * 8) =
                    *(const int4*)&Xs[(wv * 16 + r) * 136 + c8 * 8];
        }
    } else {                               // F_OUT = 40: 5 int4 per row
        for (int g = lane; g < 80; g += 64) {
            int r = g / 5, seg = g - r * 5;
            int row = row0 + wv * 16 + r;
            if (row < N_NODES)
                *(int4*)((__half*)H + (size_t)row * 40 + seg * 8) =
                    *(const int4*)&Xs[(wv * 16 + r) * 136 + seg * 8];
        }
    }
}

// ---------------- sort scans ----------------

__global__ __launch_bounds__(256) void scan1_k(int* __restrict__ gh, int* __restrict__ total) {
    __shared__ int s[256];
    int t = threadIdx.x, b = blockIdx.x;
    int v = gh[t * NBUCK + b];
    s[t] = v;
    __syncthreads();
    int x = v;
    for (int off = 1; off < 256; off <<= 1) {
        int u = (t >= off) ? s[t - off] : 0;
        __syncthreads();
        x += u; s[t] = x;
        __syncthreads();
    }
    gh[t * NBUCK + b] = x - v;            // exclusive within bucket
    if (t == 255) total[b] = x;
}

__global__ __launch_bounds__(256) void scan2_k(const int* __restrict__ total,
                                               int* __restrict__ bbase) {
    __shared__ int s[256];
    int t = threadIdx.x;
    int v = (t < NBUCK) ? total[t] : 0;
    s[t] = v;
    __syncthreads();
    int x = v;
    for (int off = 1; off < 256; off <<= 1) {
        int u = (t >= off) ? s[t - off] : 0;
        __syncthreads();
        x += u; s[t] = x;
        __syncthreads();
    }
    if (t <= NBUCK) bbase[t] = x - v;
}

// ---------------- bucket scatter (LDS cursors, no global atomics) ----------------

__global__ __launch_bounds__(256) void bucket_k(const int* __restrict__ src,
        const int* __restrict__ dst, const float* __restrict__ ew,
        const int* __restrict__ gh, const int* __restrict__ bbase,
        int2* __restrict__ bkt) {
    __shared__ int cur[256];
    int t = threadIdx.x, b = blockIdx.x;
    if (t < NBUCK) cur[t] = bbase[t] + gh[b * NBUCK + t];
    __syncthreads();
    int e0 = b * EPB;
    for (int j = t; j < EPB; j += 256) {
        int d = dst[e0 + j];
        int pos = atomicAdd(&cur[d >> 8], 1);
        bkt[pos] = make_int2(src[e0 + j] | (d << 16), __float_as_int(ew[e0 + j]));
    }
}

// ---------------- finalize: per-bucket dst sort + rowptr + dinv ----------------

__global__ __launch_bounds__(256) void final_k(const int2* __restrict__ bkt,
        const int* __restrict__ bbase, int2* __restrict__ ev,
        int* __restrict__ rowptr, float* __restrict__ dinv) {
    __shared__ int   cnt[256];
    __shared__ float wsum[256];
    __shared__ int   s[256];
    int t = threadIdx.x, b = blockIdx.x;
    int base = bbase[b], cntb = bbase[b + 1] - base;
    cnt[t] = 0; wsum[t] = 0.f;
    __syncthreads();
    for (int j = t; j < cntb; j += 256) {
        int2 r = bkt[base + j];
        int bin = (r.x >> 16) & 255;
        atomicAdd(&cnt[bin], 1);
        atomicAdd(&wsum[bin], __int_as_float(r.y));
    }
    __syncthreads();
    int v = cnt[t];
    s[t] = v;
    __syncthreads();
    int x = v;
    for (int off = 1; off < 256; off <<= 1) {
        int u = (t >= off) ? s[t - off] : 0;
        __syncthreads();
        x += u; s[t] = x;
        __syncthreads();
    }
    int off_t = x - v;
    int nd = b * 256 + t;
    if (nd < N_NODES) {
        rowptr[nd] = base + off_t;
        dinv[nd] = rsqrtf(1.0f + wsum[t]);
    }
    if (b == 0 && t == 0) rowptr[N_NODES] = N_EDGES;
    s[t] = off_t;
    __syncthreads();
    for (int j = t; j < cntb; j += 256) {
        int2 r = bkt[base + j];
        int bin = (r.x >> 16) & 255;
        int p = atomicAdd(&s[bin], 1);
        ev[base + p] = make_int2(r.x & 0xFFFF, r.y);
    }
}

// ---------------- Aggregation, 128 half features ----------------
// out_i = relu( dinv_i*( sum_e ew*dinv[src]*h[src] + dinv_i*h_i ) + bias ), half out

__global__ __launch_bounds__(256) void agg128_k(const __half* __restrict__ H,
        const int2* __restrict__ ev, const int* __restrict__ rowptr,
        const float* __restrict__ dinv, const float* __restrict__ bias,
        __half* __restrict__ out) {
    int lane = threadIdx.x & 63;
    int node = __builtin_amdgcn_readfirstlane(blockIdx.x * 4 + (threadIdx.x >> 6));
    if (node >= N_NODES) return;
    const __half2* __restrict__ H2 = (const __half2*)H;
    float di = dinv[node];
    float2 hs = __half22float2(H2[(size_t)node * 64 + lane]);
    float ax = di * hs.x, ay = di * hs.y;
    int e0 = rowptr[node], e1 = rowptr[node + 1];
    int e = e0;
    for (; e + 4 <= e1; e += 4) {
        int2 p0 = ev[e + 0];
        int2 p1 = ev[e + 1];
        int2 p2 = ev[e + 2];
        int2 p3 = ev[e + 3];
        float d0 = dinv[p0.x], d1 = dinv[p1.x], d2 = dinv[p2.x], d3 = dinv[p3.x];
        float2 g0 = __half22float2(H2[(size_t)p0.x * 64 + lane]);
        float2 g1 = __half22float2(H2[(size_t)p1.x * 64 + lane]);
        float2 g2 = __half22float2(H2[(size_t)p2.x * 64 + lane]);
        float2 g3 = __half22float2(H2[(size_t)p3.x * 64 + lane]);
        float v0 = __int_as_float(p0.y) * d0;
        float v1 = __int_as_float(p1.y) * d1;
        float v2 = __int_as_float(p2.y) * d2;
        float v3 = __int_as_float(p3.y) * d3;
        ax = fmaf(v0, g0.x, ax); ay = fmaf(v0, g0.y, ay);
        ax = fmaf(v1, g1.x, ax); ay = fmaf(v1, g1.y, ay);
        ax = fmaf(v2, g2.x, ax); ay = fmaf(v2, g2.y, ay);
        ax = fmaf(v3, g3.x, ax); ay = fmaf(v3, g3.y, ay);
    }
    for (; e < e1; e++) {
        int2 p = ev[e];
        float v = __int_as_float(p.y) * dinv[p.x];
        float2 g = __half22float2(H2[(size_t)p.x * 64 + lane]);
        ax = fmaf(v, g.x, ax);
        ay = fmaf(v, g.y, ay);
    }
    float2 b = *(const float2*)&bias[2 * lane];
    ax = fmaxf(fmaf(ax, di, b.x), 0.f);
    ay = fmaxf(fmaf(ay, di, b.y), 0.f);
    ((__half2*)out)[(size_t)node * 64 + lane] = __float22half2_rn(make_float2(ax, ay));
}

// ---------------- Aggregation, 40 half features -> fp32 out with bias ----------------

__global__ __launch_bounds__(256) void agg40_k(const __half* __restrict__ Y,
        const int2* __restrict__ ev, const int* __restrict__ rowptr,
        const float* __restrict__ dinv, const float* __restrict__ bias,
        float* __restrict__ out) {
    int lane = threadIdx.x & 63;
    int node = __builtin_amdgcn_readfirstlane(blockIdx.x * 4 + (threadIdx.x >> 6));
    if (node >= N_NODES) return;
    const __half2* __restrict__ Y2 = (const __half2*)Y;
    int f = (lane < 20) ? lane : 0;            // feature pair index
    float di = dinv[node];
    float2 ys = __half22float2(Y2[(size_t)node * 20 + f]);
    float ax = di * ys.x, ay = di * ys.y;
    int e0 = rowptr[node], e1 = rowptr[node + 1];
    int e = e0;
    for (; e + 4 <= e1; e += 4) {
        int2 p0 = ev[e + 0];
        int2 p1 = ev[e + 1];
        int2 p2 = ev[e + 2];
        int2 p3 = ev[e + 3];
        float d0 = dinv[p0.x], d1 = dinv[p1.x], d2 = dinv[p2.x], d3 = dinv[p3.x];
        float2 g0 = __half22float2(Y2[(size_t)p0.x * 20 + f]);
        float2 g1 = __half22float2(Y2[(size_t)p1.x * 20 + f]);
        float2 g2 = __half22float2(Y2[(size_t)p2.x * 20 + f]);
        float2 g3 = __half22float2(Y2[(size_t)p3.x * 20 + f]);
        float v0 = __int_as_float(p0.y) * d0;
        float v1 = __int_as_float(p1.y) * d1;
        float v2 = __int_as_float(p2.y) * d2;
        float v3 = __int_as_float(p3.y) * d3;
        ax = fmaf(v0, g0.x, ax); ay = fmaf(v0, g0.y, ay);
        ax = fmaf(v1, g1.x, ax); ay = fmaf(v1, g1.y, ay);
        ax = fmaf(v2, g2.x, ax); ay = fmaf(v2, g2.y, ay);
        ax = fmaf(v3, g3.x, ax); ay = fmaf(v3, g3.y, ay);
    }
    for (; e < e1; e++) {
        int2 p = ev[e];
        float v = __int_as_float(p.y) * dinv[p.x];
        float2 g = __half22float2(Y2[(size_t)p.x * 20 + f]);
        ax = fmaf(v, g.x, ax);
        ay = fmaf(v, g.y, ay);
    }
    if (lane < 20) {
        float2 b = *(const float2*)&bias[2 * lane];
        float2 o;
        o.x = fmaf(ax, di, b.x);
        o.y = fmaf(ay, di, b.y);
        *(float2*)&out[(size_t)node * 40 + 2 * lane] = o;
    }
}

// ---------------- launch ----------------

extern "C" void kernel_launch(void* const* d_in, const int* in_sizes, int n_in,
                              void* d_out, int out_size, void* d_ws, size_t ws_size,
                              hipStream_t stream) {
    const float* x  = (const float*)d_in[0];
    const int*   ei = (const int*)d_in[1];
    const int*   src = ei;
    const int*   dst = ei + N_EDGES;
    const float* ew = (const float*)d_in[2];
    const float* W1 = (const float*)d_in[3];
    const float* b1 = (const float*)d_in[4];
    const float* W2 = (const float*)d_in[5];
    const float* b2 = (const float*)d_in[6];
    const float* W3 = (const float*)d_in[7];
    const float* b3 = (const float*)d_in[8];
    float* out = (float*)d_out;

    char* w = (char*)d_ws;
    auto alloc = [&](size_t bytes) {
        char* p = w;
        w += (bytes + 255) & ~(size_t)255;
        return p;
    };
    float*     dinv   = (float*)    alloc((size_t)N_NODES * 4);
    int*       rowptr = (int*)      alloc((size_t)(N_NODES + 1) * 4);
    int*       gh     = (int*)      alloc((size_t)NBLK * NBUCK * 4);
    int*       total  = (int*)      alloc((size_t)NBUCK * 4);
    int*       bbase  = (int*)      alloc((size_t)(NBUCK + 1) * 4);
    int2*      bkt    = (int2*)     alloc((size_t)N_EDGES * 8);
    int2*      ev     = (int2*)     alloc((size_t)N_EDGES * 8);
    __half*    hbuf   = (__half*)   alloc((size_t)N_NODES * 128 * 2);
    __half*    abuf   = (__half*)   alloc((size_t)N_NODES * 128 * 2);
    __half*    ybuf   = (__half*)   alloc((size_t)N_NODES * 40 * 2);
    _Float16*  Wt1    = (_Float16*) alloc((size_t)128 * 128 * 2);
    _Float16*  Wt2    = (_Float16*) alloc((size_t)128 * 128 * 2);
    _Float16*  Wt3    = (_Float16*) alloc((size_t)48 * 128 * 2);

    constexpr int GA = (N_NODES + 3) / 4;

    wconv_k<<<152, 256, 0, stream>>>(W1, W2, W3, Wt1, Wt2, Wt3);
    // fused: P1 bucket histogram + gemm1 (x @ W1 -> hbuf half, MFMA)
    gemm_mfma_k<float, 128, 8, true><<<NBLK + GBM, 256, 0, stream>>>(x, Wt1, hbuf, dst, gh);
    scan1_k<<<NBUCK, 256, 0, stream>>>(gh, total);
    scan2_k<<<1, 256, 0, stream>>>(total, bbase);
    bucket_k<<<NBLK, 256, 0, stream>>>(src, dst, ew, gh, bbase, bkt);
    final_k<<<NBUCK, 256, 0, stream>>>(bkt, bbase, ev, rowptr, dinv);

    agg128_k<<<GA, 256, 0, stream>>>(hbuf, ev, rowptr, dinv, b1, abuf);
    gemm_mfma_k<__half, 128, 8, false><<<GBM, 256, 0, stream>>>(abuf, Wt2, hbuf, nullptr, nullptr);
    agg128_k<<<GA, 256, 0, stream>>>(hbuf, ev, rowptr, dinv, b2, abuf);
    gemm_mfma_k<__half, 40, 3, false><<<GBM, 256, 0, stream>>>(abuf, Wt3, ybuf, nullptr, nullptr);
    agg40_k<<<GA, 256, 0, stream>>>(ybuf, ev, rowptr, dinv, b3, out);
}